// Round 2
// baseline (550.085 us; speedup 1.0000x reference)
//
#include <hip/hip_runtime.h>

#define HIDDEN 2048
#define NHEADS 32
#define NKV 8
#define HD 64
#define QLEN 2048

typedef short bf16x8 __attribute__((ext_vector_type(8)));
typedef float f32x4 __attribute__((ext_vector_type(4)));

static __device__ __forceinline__ unsigned short f2bf(float f) {
  unsigned int u = __float_as_uint(f);
  u += 0x7fff + ((u >> 16) & 1);   // RNE
  return (unsigned short)(u >> 16);
}
static __device__ __forceinline__ float bf2f(unsigned short h) {
  return __uint_as_float(((unsigned int)h) << 16);
}

// ---------------- f32 -> bf16 convert (vectorized) ----------------
__global__ void cvt_kernel(const float* __restrict__ in, unsigned short* __restrict__ out, int n4) {
  int i = blockIdx.x * blockDim.x + threadIdx.x;
  if (i >= n4) return;
  float4 v = ((const float4*)in)[i];
  ushort4 o;
  o.x = f2bf(v.x); o.y = f2bf(v.y); o.z = f2bf(v.z); o.w = f2bf(v.w);
  ((ushort4*)out)[i] = o;
}

// ---------------- RoPE cos/sin table: [pos][j], j=0..31 ----------------
__global__ void rope_table_kernel(const int* __restrict__ pid, float* __restrict__ cost, float* __restrict__ sint) {
  int t = blockIdx.x * blockDim.x + threadIdx.x;   // 2048*32
  if (t >= QLEN * 32) return;
  int pos = t >> 5, j = t & 31;
  float p = (float)pid[pos];
  // inv_freq = 10000^(-j/32) = exp2(-j * log2(10000)/32)
  float inv = exp2f(-(float)j * 0.41524101187358740f);
  float f = p * inv;
  cost[t] = cosf(f);
  sint[t] = sinf(f);
}

// ---------------- head-mask (top-16 of 32 logits, f32/f64 exact) ----------------
__global__ __launch_bounds__(256) void headmask_kernel(const float* __restrict__ hs,
                                                       const float* __restrict__ Wpred,
                                                       float* __restrict__ mask) {
  int q = blockIdx.x;
  int tid = threadIdx.x;
  int w = tid >> 6, l = tid & 63;
  __shared__ float logits[NHEADS];
  const float* hr = hs + (size_t)q * HIDDEN;
  for (int hh = 0; hh < 8; ++hh) {
    int h = w * 8 + hh;
    const float* wr = Wpred + (size_t)h * HIDDEN;
    double acc = 0.0;
    for (int i = l; i < HIDDEN; i += 64)
      acc += (double)hr[i] * (double)wr[i];
    for (int off = 32; off; off >>= 1)
      acc += __shfl_down(acc, off);
    if (l == 0) logits[h] = (float)acc;
  }
  __syncthreads();
  if (tid < NHEADS) {
    float mine = logits[tid];
    int rank = 0;
    for (int j = 0; j < NHEADS; ++j) {
      float oj = logits[j];
      if (oj > mine || (oj == mine && j < tid)) ++rank;   // jax top_k stable tie-break
    }
    mask[(size_t)tid * QLEN + q] = (rank < 16) ? 1.0f : 0.0f;
  }
}

// ---------------- RoPE apply in-place on bf16 (pos, h*64+d) buffer ----------------
__global__ void rope_apply_kernel(unsigned short* __restrict__ X,
                                  const float* __restrict__ cost, const float* __restrict__ sint,
                                  int nh, float scale, int total) {
  int t = blockIdx.x * blockDim.x + threadIdx.x;
  if (t >= total) return;
  int j = t & 31;
  int h = (t >> 5) % nh;
  int pos = t / (32 * nh);
  size_t base = (size_t)pos * (nh * HD) + h * HD;
  float x0 = bf2f(X[base + j]);
  float x1 = bf2f(X[base + 32 + j]);
  float c = cost[pos * 32 + j];
  float s = sint[pos * 32 + j];
  X[base + j]      = f2bf((x0 * c - x1 * s) * scale);
  X[base + 32 + j] = f2bf((x1 * c + x0 * s) * scale);
}

// ---------------- bf16 GEMM: C[M,N] = A[M,K] * B[N,K]^T ----------------
template<bool OUT_BF16>
__global__ __launch_bounds__(256) void gemm_bt_kernel(const unsigned short* __restrict__ A,
                                                      const unsigned short* __restrict__ B,
                                                      void* __restrict__ Cout,
                                                      int N, int K) {
  const int LDT = 40;  // padded row stride (elems), 80B
  __shared__ __align__(16) unsigned short As[128 * LDT];
  __shared__ __align__(16) unsigned short Bs[128 * LDT];
  int n0 = blockIdx.x * 128;
  int m0 = blockIdx.y * 128;
  int tid = threadIdx.x;
  int l = tid & 63, w = tid >> 6;
  int lr = l & 15, lg = l >> 4;
  int wm = (w >> 1) * 64, wn = (w & 1) * 64;
  int srow = tid >> 2;          // 0..63
  int scol = (tid & 3) * 8;     // 0,8,16,24
  f32x4 acc[4][4] = {};
  for (int k0 = 0; k0 < K; k0 += 32) {
#pragma unroll
    for (int c = 0; c < 2; ++c) {
      int r = srow + c * 64;
      uint4 va = *(const uint4*)(A + (size_t)(m0 + r) * K + k0 + scol);
      *(uint4*)(&As[r * LDT + scol]) = va;
      uint4 vb = *(const uint4*)(B + (size_t)(n0 + r) * K + k0 + scol);
      *(uint4*)(&Bs[r * LDT + scol]) = vb;
    }
    __syncthreads();
    bf16x8 af[4], bfr[4];
#pragma unroll
    for (int m = 0; m < 4; ++m)
      af[m] = *(const bf16x8*)(&As[(wm + m * 16 + lr) * LDT + lg * 8]);
#pragma unroll
    for (int n = 0; n < 4; ++n)
      bfr[n] = *(const bf16x8*)(&Bs[(wn + n * 16 + lr) * LDT + lg * 8]);
#pragma unroll
    for (int m = 0; m < 4; ++m)
#pragma unroll
      for (int n = 0; n < 4; ++n)
        acc[m][n] = __builtin_amdgcn_mfma_f32_16x16x32_bf16(af[m], bfr[n], acc[m][n], 0, 0, 0);
    __syncthreads();
  }
#pragma unroll
  for (int m = 0; m < 4; ++m) {
    int row = m0 + wm + m * 16 + lg * 4;
#pragma unroll
    for (int n = 0; n < 4; ++n) {
      int col = n0 + wn + n * 16 + lr;
#pragma unroll
      for (int r = 0; r < 4; ++r) {
        if (OUT_BF16)
          ((unsigned short*)Cout)[(size_t)(row + r) * N + col] = f2bf(acc[m][n][r]);
        else
          ((float*)Cout)[(size_t)(row + r) * N + col] = acc[m][n][r];
      }
    }
  }
}

// ---------------- flash attention (GQA, causal) ----------------
// Q pre-scaled by 1/8. grid = (QLEN/64, NHEADS), block = 256 (4 waves x 16 q-rows).
__global__ __launch_bounds__(256) void attn_kernel(const unsigned short* __restrict__ Q,
                                                   const unsigned short* __restrict__ K,
                                                   const unsigned short* __restrict__ V,
                                                   const float* __restrict__ mask,
                                                   unsigned short* __restrict__ AO) {
  __shared__ __align__(16) unsigned short Ks[64 * 72];
  __shared__ __align__(16) unsigned short Vt[64 * 72];   // [d][key], key-block XOR swizzled
  __shared__ __align__(16) unsigned short Pl[4 * 16 * 72];
  int bx = blockIdx.x;
  int h = blockIdx.y;
  int kvh = h >> 2;
  int q0 = bx * 64;
  int tid = threadIdx.x;
  int w = tid >> 6, l = tid & 63;
  int lr = l & 15, lg = l >> 4;

  bf16x8 qa[2];
  {
    int qrow = q0 + w * 16 + lr;
    const unsigned short* qp = Q + (size_t)qrow * HIDDEN + h * HD + lg * 8;
    qa[0] = *(const bf16x8*)(qp);
    qa[1] = *(const bf16x8*)(qp + 32);
  }
  f32x4 accO[4] = {};
  float mR[4], sR[4];
#pragma unroll
  for (int r = 0; r < 4; ++r) { mR[r] = -1e30f; sR[r] = 0.f; }

  int srow = tid >> 3;          // key row 0..31 (per pass)
  int u = tid & 7;              // d-chunk index
  int sd = u * 8;
  const float LOG2E = 1.44269504088896340736f;

  for (int kt = 0; kt <= bx; ++kt) {
    __syncthreads();
    // stage K (row-major) and V^T (swizzled)
#pragma unroll
    for (int c = 0; c < 2; ++c) {
      int key = srow + c * 32;
      const unsigned short* kp = K + (size_t)(kt * 64 + key) * (NKV * HD) + kvh * HD + sd;
      *(uint4*)(&Ks[key * 72 + sd]) = *(const uint4*)kp;
      const unsigned short* vp = V + (size_t)(kt * 64 + key) * (NKV * HD) + kvh * HD + sd;
      uint4 vv = *(const uint4*)vp;
      const unsigned short* ve = (const unsigned short*)&vv;
      int pk = key ^ (u << 3);   // swizzle: key-block XOR (d>>3), d-chunk u constant per thread
#pragma unroll
      for (int j = 0; j < 8; ++j)
        Vt[(sd + j) * 72 + pk] = ve[j];
    }
    __syncthreads();
    // S = Q K^T
    f32x4 s0[4] = {};
#pragma unroll
    for (int n = 0; n < 4; ++n) {
      bf16x8 kb0 = *(const bf16x8*)(&Ks[(n * 16 + lr) * 72 + lg * 8]);
      bf16x8 kb1 = *(const bf16x8*)(&Ks[(n * 16 + lr) * 72 + 32 + lg * 8]);
      s0[n] = __builtin_amdgcn_mfma_f32_16x16x32_bf16(qa[0], kb0, s0[n], 0, 0, 0);
      s0[n] = __builtin_amdgcn_mfma_f32_16x16x32_bf16(qa[1], kb1, s0[n], 0, 0, 0);
    }
    if (kt == bx) {   // diagonal tile: causal mask
#pragma unroll
      for (int n = 0; n < 4; ++n) {
        int kidx = kt * 64 + n * 16 + lr;
#pragma unroll
        for (int r = 0; r < 4; ++r) {
          int qidx = q0 + w * 16 + lg * 4 + r;
          if (kidx > qidx) s0[n][r] = -1e30f;
        }
      }
    }
    // online softmax (rows live on lanes sharing lg; reduce over lr via xor 1,2,4,8)
    float pr[4][4];
#pragma unroll
    for (int r = 0; r < 4; ++r) {
      float mx = fmaxf(fmaxf(s0[0][r], s0[1][r]), fmaxf(s0[2][r], s0[3][r]));
      mx = fmaxf(mx, __shfl_xor(mx, 1));
      mx = fmaxf(mx, __shfl_xor(mx, 2));
      mx = fmaxf(mx, __shfl_xor(mx, 4));
      mx = fmaxf(mx, __shfl_xor(mx, 8));
      float mnew = fmaxf(mR[r], mx);
      float sc = exp2f((mR[r] - mnew) * LOG2E);
      float rs = 0.f;
#pragma unroll
      for (int n = 0; n < 4; ++n) {
        float p = exp2f((s0[n][r] - mnew) * LOG2E);
        pr[n][r] = p; rs += p;
      }
      rs += __shfl_xor(rs, 1);
      rs += __shfl_xor(rs, 2);
      rs += __shfl_xor(rs, 4);
      rs += __shfl_xor(rs, 8);
      sR[r] = sR[r] * sc + rs;
      mR[r] = mnew;
#pragma unroll
      for (int n = 0; n < 4; ++n) accO[n][r] *= sc;
    }
    // P -> LDS (per-wave region), then read back as A-fragments
#pragma unroll
    for (int n = 0; n < 4; ++n)
#pragma unroll
      for (int r = 0; r < 4; ++r)
        Pl[w * 16 * 72 + (lg * 4 + r) * 72 + n * 16 + lr] = f2bf(pr[n][r]);
    __syncthreads();
    bf16x8 pa0 = *(const bf16x8*)(&Pl[w * 16 * 72 + lr * 72 + lg * 8]);
    bf16x8 pa1 = *(const bf16x8*)(&Pl[w * 16 * 72 + lr * 72 + 32 + lg * 8]);
#pragma unroll
    for (int n = 0; n < 4; ++n) {
      int d = n * 16 + lr;
      int g = (d >> 3) & 7;
      bf16x8 vb0 = *(const bf16x8*)(&Vt[d * 72 + ((lg * 8) ^ (g << 3))]);
      bf16x8 vb1 = *(const bf16x8*)(&Vt[d * 72 + ((32 + lg * 8) ^ (g << 3))]);
      accO[n] = __builtin_amdgcn_mfma_f32_16x16x32_bf16(pa0, vb0, accO[n], 0, 0, 0);
      accO[n] = __builtin_amdgcn_mfma_f32_16x16x32_bf16(pa1, vb1, accO[n], 0, 0, 0);
    }
  }
#pragma unroll
  for (int r = 0; r < 4; ++r) {
    int qidx = q0 + w * 16 + lg * 4 + r;
    float inv = mask[(size_t)h * QLEN + qidx] / sR[r];
#pragma unroll
    for (int n = 0; n < 4; ++n)
      AO[(size_t)qidx * HIDDEN + h * HD + n * 16 + lr] = f2bf(accO[n][r] * inv);
  }
}

// ---------------- launcher ----------------
extern "C" void kernel_launch(void* const* d_in, const int* in_sizes, int n_in,
                              void* d_out, int out_size, void* d_ws, size_t ws_size,
                              hipStream_t stream) {
  const float* hs    = (const float*)d_in[0];
  const float* Wq    = (const float*)d_in[1];
  const float* Wk    = (const float*)d_in[2];
  const float* Wv    = (const float*)d_in[3];
  const float* Wo    = (const float*)d_in[4];
  const float* Wpred = (const float*)d_in[5];
  const int*   pid   = (const int*)d_in[6];
  float* out = (float*)d_out;

  unsigned short* hsb = (unsigned short*)d_ws;          // 4194304
  unsigned short* Wqb = hsb + 4194304;                  // 4194304
  unsigned short* Wkb = Wqb + 4194304;                  // 1048576
  unsigned short* Wvb = Wkb + 1048576;                  // 1048576
  unsigned short* Wob = Wvb + 1048576;                  // 4194304
  unsigned short* Qb  = Wob + 4194304;                  // 4194304
  unsigned short* Kb  = Qb  + 4194304;                  // 1048576
  unsigned short* Vb  = Kb  + 1048576;                  // 1048576
  unsigned short* AOb = Vb  + 1048576;                  // 4194304
  float* maskb = (float*)(AOb + 4194304);               // 65536 f32
  float* cost  = maskb + 65536;                         // 65536 f32
  float* sint  = cost + 65536;                          // 65536 f32

  // converts
  cvt_kernel<<<4096, 256, 0, stream>>>(hs, hsb, 1048576);
  cvt_kernel<<<4096, 256, 0, stream>>>(Wq, Wqb, 1048576);
  cvt_kernel<<<1024, 256, 0, stream>>>(Wk, Wkb, 262144);
  cvt_kernel<<<1024, 256, 0, stream>>>(Wv, Wvb, 262144);
  cvt_kernel<<<4096, 256, 0, stream>>>(Wo, Wob, 1048576);

  rope_table_kernel<<<256, 256, 0, stream>>>(pid, cost, sint);
  headmask_kernel<<<QLEN, 256, 0, stream>>>(hs, Wpred, maskb);

  // projections
  gemm_bt_kernel<true><<<dim3(16, 16), 256, 0, stream>>>(hsb, Wqb, Qb, 2048, 2048);
  gemm_bt_kernel<true><<<dim3(4, 16), 256, 0, stream>>>(hsb, Wkb, Kb, 512, 2048);
  gemm_bt_kernel<true><<<dim3(4, 16), 256, 0, stream>>>(hsb, Wvb, Vb, 512, 2048);

  // RoPE (Q gets the 1/sqrt(64) score scale folded in; exact power of 2)
  rope_apply_kernel<<<8192, 256, 0, stream>>>(Qb, cost, sint, NHEADS, 0.125f, QLEN * NHEADS * 32);
  rope_apply_kernel<<<2048, 256, 0, stream>>>(Kb, cost, sint, NKV, 1.0f, QLEN * NKV * 32);

  attn_kernel<<<dim3(32, 32), 256, 0, stream>>>(Qb, Kb, Vb, maskb, AOb);

  // output projection -> f32
  gemm_bt_kernel<false><<<dim3(16, 16), 256, 0, stream>>>(AOb, Wob, out, 2048, 2048);
}

// Round 4
// 481.805 us; speedup vs baseline: 1.1417x; 1.1417x over previous
//
#include <hip/hip_runtime.h>
#include <hip/hip_bf16.h>

#define HIDDEN 2048
#define NHEADS 32
#define NKV 8
#define HD 64
#define QLEN 2048

typedef short bf16x8 __attribute__((ext_vector_type(8)));
typedef float f32x4 __attribute__((ext_vector_type(4)));
typedef float f32x16 __attribute__((ext_vector_type(16)));

static __device__ __forceinline__ unsigned short f2bf(float f) {
  unsigned int u = __float_as_uint(f);
  u += 0x7fff + ((u >> 16) & 1);   // RNE
  return (unsigned short)(u >> 16);
}
static __device__ __forceinline__ float bf2f(unsigned short h) {
  return __uint_as_float(((unsigned int)h) << 16);
}
static __device__ __forceinline__ unsigned pack_bf2(float lo, float hi) {
  __hip_bfloat162 h2 = __float22bfloat162_rn(make_float2(lo, hi));  // x -> low 16
  unsigned u; __builtin_memcpy(&u, &h2, 4); return u;
}

#define GL16(gsrc, ldst) \
  __builtin_amdgcn_global_load_lds((const __attribute__((address_space(1))) unsigned int*)(gsrc), \
                                   (__attribute__((address_space(3))) unsigned int*)(ldst), 16, 0, 0)
#define MFMA32(a, b, c) __builtin_amdgcn_mfma_f32_32x32x16_bf16((a), (b), (c), 0, 0, 0)

// ---------------- f32 -> bf16 convert ----------------
__global__ void cvt_kernel(const float* __restrict__ in, unsigned short* __restrict__ out, int n4) {
  int i = blockIdx.x * blockDim.x + threadIdx.x;
  if (i >= n4) return;
  float4 v = ((const float4*)in)[i];
  ushort4 o;
  o.x = f2bf(v.x); o.y = f2bf(v.y); o.z = f2bf(v.z); o.w = f2bf(v.w);
  ((ushort4*)out)[i] = o;
}

// ---------------- RoPE cos/sin table: [pos][j], j=0..31 ----------------
__global__ void rope_table_kernel(const int* __restrict__ pid, float* __restrict__ cost, float* __restrict__ sint) {
  int t = blockIdx.x * blockDim.x + threadIdx.x;
  if (t >= QLEN * 32) return;
  int pos = t >> 5, j = t & 31;
  float p = (float)pid[pos];
  float inv = exp2f(-(float)j * 0.41524101187358740f);  // log2(10000)/32
  float f = p * inv;
  cost[t] = cosf(f);
  sint[t] = sinf(f);
}

// ---------------- head-mask (top-16 of 32 logits, f32/f64 exact) ----------------
__global__ __launch_bounds__(256) void headmask_kernel(const float* __restrict__ hs,
                                                       const float* __restrict__ Wpred,
                                                       float* __restrict__ mask) {
  int q = blockIdx.x;
  int tid = threadIdx.x;
  int w = tid >> 6, l = tid & 63;
  __shared__ float logits[NHEADS];
  const float* hr = hs + (size_t)q * HIDDEN;
  for (int hh = 0; hh < 8; ++hh) {
    int h = w * 8 + hh;
    const float* wr = Wpred + (size_t)h * HIDDEN;
    double acc = 0.0;
    for (int i = l; i < HIDDEN; i += 64)
      acc += (double)hr[i] * (double)wr[i];
    for (int off = 32; off; off >>= 1)
      acc += __shfl_down(acc, off);
    if (l == 0) logits[h] = (float)acc;
  }
  __syncthreads();
  if (tid < NHEADS) {
    float mine = logits[tid];
    int rank = 0;
    for (int j = 0; j < NHEADS; ++j) {
      float oj = logits[j];
      if (oj > mine || (oj == mine && j < tid)) ++rank;   // jax top_k stable tie-break
    }
    mask[(size_t)tid * QLEN + q] = (rank < 16) ? 1.0f : 0.0f;
  }
}

// ---------------- RoPE apply in-place (K only) ----------------
__global__ void rope_apply_kernel(unsigned short* __restrict__ X,
                                  const float* __restrict__ cost, const float* __restrict__ sint,
                                  int nh, float scale, int total) {
  int t = blockIdx.x * blockDim.x + threadIdx.x;
  if (t >= total) return;
  int j = t & 31;
  int h = (t >> 5) % nh;
  int pos = t / (32 * nh);
  size_t base = (size_t)pos * (nh * HD) + h * HD;
  float x0 = bf2f(X[base + j]);
  float x1 = bf2f(X[base + 32 + j]);
  float c = cost[pos * 32 + j];
  float s = sint[pos * 32 + j];
  X[base + j]      = f2bf((x0 * c - x1 * s) * scale);
  X[base + 32 + j] = f2bf((x1 * c + x0 * s) * scale);
}

// ---------------- bf16 tile transpose: out[C][R] = in[R][C]^T ----------------
__global__ __launch_bounds__(256) void transpose_kernel(const unsigned short* __restrict__ in,
                                                        unsigned short* __restrict__ out,
                                                        int R, int C) {
  __shared__ unsigned short t[64][72];
  int r0 = blockIdx.y * 64, c0 = blockIdx.x * 64;
  int tid = threadIdx.x;
  int rr = tid >> 3;            // 0..31
  int cc = (tid & 7) * 8;       // 0..56
#pragma unroll
  for (int c = 0; c < 2; ++c) {
    int row = rr + c * 32;
    *(bf16x8*)&t[row][cc] = *(const bf16x8*)(in + (size_t)(r0 + row) * C + c0 + cc);
  }
  __syncthreads();
#pragma unroll
  for (int c = 0; c < 2; ++c) {
    int oc = rr + c * 32;       // tile column = output row
    union { unsigned short s[8]; bf16x8 v; } o;
#pragma unroll
    for (int j = 0; j < 8; ++j) o.s[j] = t[cc + j][oc];
    *(bf16x8*)(out + (size_t)(c0 + oc) * R + r0 + cc) = o.v;
  }
}

// ---------------- bf16 GEMM (m97 structure): C[M,N] = A[M,K] * B[N,K]^T ----------------
template<bool OUT_BF16>
__global__ __launch_bounds__(256) void gemm2_kernel(const unsigned short* __restrict__ A,
                                                    const unsigned short* __restrict__ B,
                                                    void* __restrict__ Cout, int N, int K) {
  __shared__ __align__(16) unsigned short As[128 * 32];
  __shared__ __align__(16) unsigned short Bs[128 * 32];
  const int tid = threadIdx.x;
  const int w = tid >> 6, l = tid & 63;
  const int lr = l & 15, lg = l >> 4;
  const int n0 = blockIdx.x * 128, m0 = blockIdx.y * 128;
  const int wm = (w >> 1) * 64, wn = (w & 1) * 64;
  f32x4 acc[4][4] = {};
  const int srow = w * 16 + (l >> 2);
  const int scol = (l & 3) * 8;
  const unsigned short* ap0 = A + (size_t)(m0 + srow) * K + scol;
  const unsigned short* ap1 = ap0 + (size_t)64 * K;
  const unsigned short* bp0 = B + (size_t)(n0 + srow) * K + scol;
  const unsigned short* bp1 = bp0 + (size_t)64 * K;
  unsigned short* asl0 = As + w * 512;
  unsigned short* asl1 = As + 2048 + w * 512;
  unsigned short* bsl0 = Bs + w * 512;
  unsigned short* bsl1 = Bs + 2048 + w * 512;
  for (int k0 = 0; k0 < K; k0 += 32) {
    GL16(ap0 + k0, asl0);
    GL16(ap1 + k0, asl1);
    GL16(bp0 + k0, bsl0);
    GL16(bp1 + k0, bsl1);
    __syncthreads();
    bf16x8 af[4], bfr[4];
#pragma unroll
    for (int m = 0; m < 4; ++m) af[m] = *(const bf16x8*)(As + (wm + m * 16 + lr) * 32 + lg * 8);
#pragma unroll
    for (int n = 0; n < 4; ++n) bfr[n] = *(const bf16x8*)(Bs + (wn + n * 16 + lr) * 32 + lg * 8);
#pragma unroll
    for (int m = 0; m < 4; ++m)
#pragma unroll
      for (int n = 0; n < 4; ++n)
        acc[m][n] = __builtin_amdgcn_mfma_f32_16x16x32_bf16(af[m], bfr[n], acc[m][n], 0, 0, 0);
    __syncthreads();
  }
#pragma unroll
  for (int m = 0; m < 4; ++m) {
    int row = m0 + wm + m * 16 + lg * 4;
#pragma unroll
    for (int n = 0; n < 4; ++n) {
      int col = n0 + wn + n * 16 + lr;
#pragma unroll
      for (int r = 0; r < 4; ++r) {
        if (OUT_BF16)
          ((unsigned short*)Cout)[(size_t)(row + r) * N + col] = f2bf(acc[m][n][r]);
        else
          ((float*)Cout)[(size_t)(row + r) * N + col] = acc[m][n][r];
      }
    }
  }
}

// ---------------- flash attention v3: swapped-QK 32x32, GQA, causal ----------------
// grid = (32 qtiles, 32 heads), block = 128 (2 waves x 32 q-rows).
// K staged [key][64d] and V^T staged [d][64key], both GL16 + XOR-swizzle, double-buffered.
// Q raw (rope fused, 0.125 scale folded); K pre-roped; VT pre-transposed global.
__global__ __launch_bounds__(128) void attn3_kernel(const unsigned short* __restrict__ Q,
                                                    const unsigned short* __restrict__ K,
                                                    const unsigned short* __restrict__ VT,
                                                    const float* __restrict__ cost,
                                                    const float* __restrict__ sint,
                                                    const float* __restrict__ mask,
                                                    unsigned short* __restrict__ AO) {
  __shared__ __align__(16) unsigned short sm[2][8192];   // per buf: K 4096 elems | VT 4096 elems
  const int tid = threadIdx.x;
  const int w = tid >> 6, l = tid & 63;
  const int hi = l >> 5, l31 = l & 31;
  const int h = blockIdx.y, kvh = h >> 2;
  const int qt = blockIdx.x;
  const int qrow = qt * 64 + w * 32 + l31;
  const float L2E = 1.44269504088896340736f;
  const int swz = (l & 7) << 4;
  const int hi16 = hi << 4;

  // staging geometry: call r, wave w covers 8 LDS rows starting (r*2+w)*8; lane l -> row +(l>>3), chunk c16=l&7
  const int strow = l >> 3;
  const int scol = ((l & 7) ^ strow) * 8;    // pre-swizzled source column (elems)
  const unsigned short* kp0 = K + (size_t)((0 + w) * 8 + strow) * 512 + kvh * 64 + scol;
  const unsigned short* kp1 = K + (size_t)((2 + w) * 8 + strow) * 512 + kvh * 64 + scol;
  const unsigned short* kp2 = K + (size_t)((4 + w) * 8 + strow) * 512 + kvh * 64 + scol;
  const unsigned short* kp3 = K + (size_t)((6 + w) * 8 + strow) * 512 + kvh * 64 + scol;
  const unsigned short* vp0 = VT + (size_t)(kvh * 64 + (0 + w) * 8 + strow) * QLEN + scol;
  const unsigned short* vp1 = VT + (size_t)(kvh * 64 + (2 + w) * 8 + strow) * QLEN + scol;
  const unsigned short* vp2 = VT + (size_t)(kvh * 64 + (4 + w) * 8 + strow) * QLEN + scol;
  const unsigned short* vp3 = VT + (size_t)(kvh * 64 + (6 + w) * 8 + strow) * QLEN + scol;

#define STAGE(kt_, b_) do { \
    const size_t kko_ = (size_t)(kt_) * 32768; \
    const size_t vko_ = (size_t)(kt_) * 64; \
    unsigned short* smb_ = &sm[b_][0]; \
    GL16(kp0 + kko_, smb_ + (0 + w) * 512); \
    GL16(kp1 + kko_, smb_ + (2 + w) * 512); \
    GL16(kp2 + kko_, smb_ + (4 + w) * 512); \
    GL16(kp3 + kko_, smb_ + (6 + w) * 512); \
    GL16(vp0 + vko_, smb_ + 4096 + (0 + w) * 512); \
    GL16(vp1 + vko_, smb_ + 4096 + (2 + w) * 512); \
    GL16(vp2 + vko_, smb_ + 4096 + (4 + w) * 512); \
    GL16(vp3 + vko_, smb_ + 4096 + (6 + w) * 512); \
  } while (0)

  // ---- load Q (B-frag layout) + fused RoPE, scale 0.125 ----
  const unsigned short* qp = Q + (size_t)qrow * HIDDEN + h * HD + hi * 8;
  bf16x8 qv0 = *(const bf16x8*)qp;
  bf16x8 qv1 = *(const bf16x8*)(qp + 16);
  bf16x8 qv2 = *(const bf16x8*)(qp + 32);
  bf16x8 qv3 = *(const bf16x8*)(qp + 48);
  const float* cbp = cost + qrow * 32 + hi * 8;
  const float* sbp = sint + qrow * 32 + hi * 8;
  f32x4 ca0 = *(const f32x4*)cbp,        ca1 = *(const f32x4*)(cbp + 4);
  f32x4 cB0 = *(const f32x4*)(cbp + 16), cB1 = *(const f32x4*)(cbp + 20);
  f32x4 sa0 = *(const f32x4*)sbp,        sa1 = *(const f32x4*)(sbp + 4);
  f32x4 sB0 = *(const f32x4*)(sbp + 16), sB1 = *(const f32x4*)(sbp + 20);
  bf16x8 qr0, qr1, qr2, qr3;
#pragma unroll
  for (int j = 0; j < 8; ++j) {
    float cosA = j < 4 ? ca0[j] : ca1[j - 4];
    float sinA = j < 4 ? sa0[j] : sa1[j - 4];
    float cosB = j < 4 ? cB0[j] : cB1[j - 4];
    float sinB = j < 4 ? sB0[j] : sB1[j - 4];
    float x0 = bf2f((unsigned short)qv0[j]);
    float x1 = bf2f((unsigned short)qv1[j]);
    float x2 = bf2f((unsigned short)qv2[j]);
    float x3 = bf2f((unsigned short)qv3[j]);
    qr0[j] = (short)f2bf((x0 * cosA - x2 * sinA) * 0.125f);
    qr1[j] = (short)f2bf((x1 * cosB - x3 * sinB) * 0.125f);
    qr2[j] = (short)f2bf((x2 * cosA + x0 * sinA) * 0.125f);
    qr3[j] = (short)f2bf((x3 * cosB + x1 * sinB) * 0.125f);
  }

  f32x16 O0 = {}, O1 = {};
  float mR = -1e30f, sR = 0.f;
  int cur = 0;
  STAGE(0, 0);
  __syncthreads();

  for (int kt = 0; kt <= qt; ++kt) {
    if (kt < qt) STAGE(kt + 1, cur ^ 1);   // async prefetch into other buffer

    const char* Kc = (const char*)&sm[cur][0];
    const char* Vc = Kc + 8192;

    // ---- S^T = K * Q^T : C[key][q], col = l31 = q ----
    f32x16 sA = {}, sB = {};
#define KF(half, dc) (*(const bf16x8*)(Kc + (((half) * 32 + l31) << 7) + ((((dc) * 32 + hi16)) ^ swz)))
    sA = MFMA32(KF(0, 0), qr0, sA);
    sA = MFMA32(KF(0, 1), qr1, sA);
    sA = MFMA32(KF(0, 2), qr2, sA);
    sA = MFMA32(KF(0, 3), qr3, sA);
    sB = MFMA32(KF(1, 0), qr0, sB);
    sB = MFMA32(KF(1, 1), qr1, sB);
    sB = MFMA32(KF(1, 2), qr2, sB);
    sB = MFMA32(KF(1, 3), qr3, sB);
#undef KF

    if (kt == qt) {   // causal mask on diagonal tile
      const int wql = w * 32 + l31;
#pragma unroll
      for (int r = 0; r < 16; ++r) {
        int key = (r & 3) + 8 * (r >> 2) + 4 * hi;
        if (key > wql) sA[r] = -1e30f;
        if (32 + key > wql) sB[r] = -1e30f;
      }
    }

    // ---- online softmax: lane owns q-row qrow; 32 in-lane values + partner via xor 32 ----
    float mx = -1e30f;
#pragma unroll
    for (int r = 0; r < 16; ++r) mx = fmaxf(mx, sA[r]);
#pragma unroll
    for (int r = 0; r < 16; ++r) mx = fmaxf(mx, sB[r]);
    mx = fmaxf(mx, __shfl_xor(mx, 32));
    bool renorm = __any(mx - mR > 8.0f);   // defer-max (T13)
    if (renorm) {
      float mn = fmaxf(mR, mx);
      float sc = exp2f((mR - mn) * L2E);
      mR = mn;
      sR *= sc;
#pragma unroll
      for (int r = 0; r < 16; ++r) { O0[r] *= sc; O1[r] *= sc; }
    }
    const float mL = mR * L2E;
    float rs = 0.f;
#pragma unroll
    for (int r = 0; r < 16; ++r) { float p = exp2f(__builtin_fmaf(sA[r], L2E, -mL)); sA[r] = p; rs += p; }
#pragma unroll
    for (int r = 0; r < 16; ++r) { float p = exp2f(__builtin_fmaf(sB[r], L2E, -mL)); sB[r] = p; rs += p; }
    rs += __shfl_xor(rs, 32);
    sR += rs;

    // ---- P -> bf16 B-frags in-register (pack + half-exchange) ----
    bf16x8 pf[4];
#pragma unroll
    for (int kc = 0; kc < 4; ++kc) {
      const int r0 = (kc & 1) * 8;
      float p0, p1, p2, p3, p4, p5, p6, p7;
      if (kc & 2) { p0 = sB[r0+0]; p1 = sB[r0+1]; p2 = sB[r0+2]; p3 = sB[r0+3];
                    p4 = sB[r0+4]; p5 = sB[r0+5]; p6 = sB[r0+6]; p7 = sB[r0+7]; }
      else        { p0 = sA[r0+0]; p1 = sA[r0+1]; p2 = sA[r0+2]; p3 = sA[r0+3];
                    p4 = sA[r0+4]; p5 = sA[r0+5]; p6 = sA[r0+6]; p7 = sA[r0+7]; }
      unsigned a_ = pack_bf2(p0, p1);
      unsigned c_ = pack_bf2(p2, p3);
      unsigned b_ = pack_bf2(p4, p5);
      unsigned d_ = pack_bf2(p6, p7);
      unsigned ax = __shfl_xor(a_, 32), bx = __shfl_xor(b_, 32);
      unsigned cx = __shfl_xor(c_, 32), dx = __shfl_xor(d_, 32);
      union { unsigned u[4]; bf16x8 v; } uu;
      uu.u[0] = hi ? bx : a_;
      uu.u[1] = hi ? dx : c_;
      uu.u[2] = hi ? b_ : ax;
      uu.u[3] = hi ? d_ : cx;
      pf[kc] = uu.v;
    }

    // ---- PV: O^T += V^T * P^T (A-frag = swizzled ds_read_b128 of VT tile) ----
#define VF(n, kc) (*(const bf16x8*)(Vc + (((n) * 32 + l31) << 7) + ((((kc) * 32 + hi16)) ^ swz)))
    O0 = MFMA32(VF(0, 0), pf[0], O0);
    O1 = MFMA32(VF(1, 0), pf[0], O1);
    O0 = MFMA32(VF(0, 1), pf[1], O0);
    O1 = MFMA32(VF(1, 1), pf[1], O1);
    O0 = MFMA32(VF(0, 2), pf[2], O0);
    O1 = MFMA32(VF(1, 2), pf[2], O1);
    O0 = MFMA32(VF(0, 3), pf[3], O0);
    O1 = MFMA32(VF(1, 3), pf[3], O1);
#undef VF

    __syncthreads();
    cur ^= 1;
  }

  // ---- epilogue: lane owns q = qrow; rows of O are d ----
  float msk = mask[(size_t)h * QLEN + qrow];
  float inv = msk / sR;
  unsigned short* aop = AO + (size_t)qrow * HIDDEN + h * HD;
#pragma unroll
  for (int rp = 0; rp < 8; ++rp) {
    int r = rp * 2;
    int d0 = (r & 3) + 8 * (r >> 2) + 4 * hi;
    *(unsigned*)(aop + d0)      = pack_bf2(O0[r] * inv, O0[r + 1] * inv);
    *(unsigned*)(aop + 32 + d0) = pack_bf2(O1[r] * inv, O1[r + 1] * inv);
  }
#undef STAGE
}

// ---------------- launcher ----------------
extern "C" void kernel_launch(void* const* d_in, const int* in_sizes, int n_in,
                              void* d_out, int out_size, void* d_ws, size_t ws_size,
                              hipStream_t stream) {
  const float* hs    = (const float*)d_in[0];
  const float* Wq    = (const float*)d_in[1];
  const float* Wk    = (const float*)d_in[2];
  const float* Wv    = (const float*)d_in[3];
  const float* Wo    = (const float*)d_in[4];
  const float* Wpred = (const float*)d_in[5];
  const int*   pid   = (const int*)d_in[6];
  float* out = (float*)d_out;

  unsigned short* hsb = (unsigned short*)d_ws;          // 4194304
  unsigned short* Wqb = hsb + 4194304;                  // 4194304
  unsigned short* Wkb = Wqb + 4194304;                  // 1048576
  unsigned short* Wvb = Wkb + 1048576;                  // 1048576
  unsigned short* Wob = Wvb + 1048576;                  // 4194304
  unsigned short* Qb  = Wob + 4194304;                  // 4194304
  unsigned short* Kb  = Qb  + 4194304;                  // 1048576
  unsigned short* Vb  = Kb  + 1048576;                  // 1048576
  unsigned short* AOb = Vb  + 1048576;                  // 4194304
  float* maskb = (float*)(AOb + 4194304);               // 65536 f32
  float* cost  = maskb + 65536;                         // 65536 f32
  float* sint  = cost + 65536;                          // 65536 f32
  unsigned short* VTb = hsb;   // hsb is dead after the 3 projection GEMMs; reuse for V^T

  cvt_kernel<<<4096, 256, 0, stream>>>(hs, hsb, 1048576);
  cvt_kernel<<<4096, 256, 0, stream>>>(Wq, Wqb, 1048576);
  cvt_kernel<<<1024, 256, 0, stream>>>(Wk, Wkb, 262144);
  cvt_kernel<<<1024, 256, 0, stream>>>(Wv, Wvb, 262144);
  cvt_kernel<<<4096, 256, 0, stream>>>(Wo, Wob, 1048576);

  rope_table_kernel<<<256, 256, 0, stream>>>(pid, cost, sint);
  headmask_kernel<<<QLEN, 256, 0, stream>>>(hs, Wpred, maskb);

  gemm2_kernel<true><<<dim3(16, 16), 256, 0, stream>>>(hsb, Wqb, Qb, 2048, 2048);
  gemm2_kernel<true><<<dim3(4, 16), 256, 0, stream>>>(hsb, Wkb, Kb, 512, 2048);
  gemm2_kernel<true><<<dim3(4, 16), 256, 0, stream>>>(hsb, Wvb, Vb, 512, 2048);

  // K rope (Q rope fused into attention)
  rope_apply_kernel<<<2048, 256, 0, stream>>>(Kb, cost, sint, NKV, 1.0f, QLEN * NKV * 32);

  // V^T (hsb no longer needed)
  transpose_kernel<<<dim3(8, 32), 256, 0, stream>>>(Vb, VTb, QLEN, NKV * HD);

  attn3_kernel<<<dim3(32, 32), 128, 0, stream>>>(Qb, Kb, VTb, cost, sint, maskb, AOb);

  gemm2_kernel<false><<<dim3(16, 16), 256, 0, stream>>>(AOb, Wob, out, 2048, 2048);
}

// Round 5
// 473.378 us; speedup vs baseline: 1.1620x; 1.0178x over previous
//
#include <hip/hip_runtime.h>
#include <hip/hip_bf16.h>

#define HIDDEN 2048
#define NHEADS 32
#define NKV 8
#define HD 64
#define QLEN 2048

typedef short bf16x8 __attribute__((ext_vector_type(8)));
typedef float f32x4 __attribute__((ext_vector_type(4)));
typedef float f32x16 __attribute__((ext_vector_type(16)));

static __device__ __forceinline__ unsigned short f2bf(float f) {
  unsigned int u = __float_as_uint(f);
  u += 0x7fff + ((u >> 16) & 1);   // RNE
  return (unsigned short)(u >> 16);
}
static __device__ __forceinline__ float bf2f(unsigned short h) {
  return __uint_as_float(((unsigned int)h) << 16);
}
static __device__ __forceinline__ unsigned pack_bf2(float lo, float hi) {
  __hip_bfloat162 h2 = __float22bfloat162_rn(make_float2(lo, hi));  // x -> low 16
  unsigned u; __builtin_memcpy(&u, &h2, 4); return u;
}

#define GL16(gsrc, ldst) \
  __builtin_amdgcn_global_load_lds((const __attribute__((address_space(1))) unsigned int*)(gsrc), \
                                   (__attribute__((address_space(3))) unsigned int*)(ldst), 16, 0, 0)
#define MFMA32(a, b, c) __builtin_amdgcn_mfma_f32_32x32x16_bf16((a), (b), (c), 0, 0, 0)

// ---------------- f32 -> bf16 convert ----------------
__global__ void cvt_kernel(const float* __restrict__ in, unsigned short* __restrict__ out, int n4) {
  int i = blockIdx.x * blockDim.x + threadIdx.x;
  if (i >= n4) return;
  float4 v = ((const float4*)in)[i];
  ushort4 o;
  o.x = f2bf(v.x); o.y = f2bf(v.y); o.z = f2bf(v.z); o.w = f2bf(v.w);
  ((ushort4*)out)[i] = o;
}

// ---------------- RoPE cos/sin table: [pos][j], j=0..31 ----------------
__global__ void rope_table_kernel(const int* __restrict__ pid, float* __restrict__ cost, float* __restrict__ sint) {
  int t = blockIdx.x * blockDim.x + threadIdx.x;
  if (t >= QLEN * 32) return;
  int pos = t >> 5, j = t & 31;
  float p = (float)pid[pos];
  float inv = exp2f(-(float)j * 0.41524101187358740f);  // log2(10000)/32
  float f = p * inv;
  cost[t] = cosf(f);
  sint[t] = sinf(f);
}

// ---------------- head-mask v2: one (q,head) pair per thread ----------------
// grid 256 x block 256: block covers 8 q-rows x 32 heads. f32 4-chunk products
// into dual f64 accumulators (error ~1e-7 << ranking margin). jax tie-break.
__global__ __launch_bounds__(256) void headmask2_kernel(const float* __restrict__ hs,
                                                        const float* __restrict__ Wpred,
                                                        float* __restrict__ mask) {
  __shared__ float lg[8][32];
  const int tid = threadIdx.x;
  const int ql = tid >> 5, hh = tid & 31;
  const int q = blockIdx.x * 8 + ql;
  const float* hr = hs + (size_t)q * HIDDEN;
  const float* wr = Wpred + (size_t)hh * HIDDEN;
  double acc0 = 0.0, acc1 = 0.0;
#pragma unroll 4
  for (int k = 0; k < HIDDEN; k += 8) {
    float4 a0 = *(const float4*)(hr + k);
    float4 b0 = *(const float4*)(wr + k);
    float4 a1 = *(const float4*)(hr + k + 4);
    float4 b1 = *(const float4*)(wr + k + 4);
    acc0 += (double)(a0.x * b0.x + a0.y * b0.y + a0.z * b0.z + a0.w * b0.w);
    acc1 += (double)(a1.x * b1.x + a1.y * b1.y + a1.z * b1.z + a1.w * b1.w);
  }
  float mine = (float)(acc0 + acc1);
  lg[ql][hh] = mine;
  __syncthreads();
  int rank = 0;
#pragma unroll
  for (int j = 0; j < NHEADS; ++j) {
    float oj = lg[ql][j];
    if (oj > mine || (oj == mine && j < hh)) ++rank;   // jax top_k stable tie-break
  }
  mask[(size_t)hh * QLEN + q] = (rank < 16) ? 1.0f : 0.0f;
}

// ---------------- RoPE apply in-place (K only) ----------------
__global__ void rope_apply_kernel(unsigned short* __restrict__ X,
                                  const float* __restrict__ cost, const float* __restrict__ sint,
                                  int nh, float scale, int total) {
  int t = blockIdx.x * blockDim.x + threadIdx.x;
  if (t >= total) return;
  int j = t & 31;
  int h = (t >> 5) % nh;
  int pos = t / (32 * nh);
  size_t base = (size_t)pos * (nh * HD) + h * HD;
  float x0 = bf2f(X[base + j]);
  float x1 = bf2f(X[base + 32 + j]);
  float c = cost[pos * 32 + j];
  float s = sint[pos * 32 + j];
  X[base + j]      = f2bf((x0 * c - x1 * s) * scale);
  X[base + 32 + j] = f2bf((x1 * c + x0 * s) * scale);
}

// ---------------- bf16 tile transpose: out[C][R] = in[R][C]^T ----------------
__global__ __launch_bounds__(256) void transpose_kernel(const unsigned short* __restrict__ in,
                                                        unsigned short* __restrict__ out,
                                                        int R, int C) {
  __shared__ unsigned short t[64][72];
  int r0 = blockIdx.y * 64, c0 = blockIdx.x * 64;
  int tid = threadIdx.x;
  int rr = tid >> 3;            // 0..31
  int cc = (tid & 7) * 8;       // 0..56
#pragma unroll
  for (int c = 0; c < 2; ++c) {
    int row = rr + c * 32;
    *(bf16x8*)&t[row][cc] = *(const bf16x8*)(in + (size_t)(r0 + row) * C + c0 + cc);
  }
  __syncthreads();
#pragma unroll
  for (int c = 0; c < 2; ++c) {
    int oc = rr + c * 32;       // tile column = output row
    union { unsigned short s[8]; bf16x8 v; } o;
#pragma unroll
    for (int j = 0; j < 8; ++j) o.s[j] = t[cc + j][oc];
    *(bf16x8*)(out + (size_t)(c0 + oc) * R + r0 + cc) = o.v;
  }
}

// ---------------- bf16 GEMM (m97 structure): C[M,N] = A[M,K] * B[N,K]^T ----------------
template<bool OUT_BF16>
__global__ __launch_bounds__(256) void gemm2_kernel(const unsigned short* __restrict__ A,
                                                    const unsigned short* __restrict__ B,
                                                    void* __restrict__ Cout, int N, int K) {
  __shared__ __align__(16) unsigned short As[128 * 32];
  __shared__ __align__(16) unsigned short Bs[128 * 32];
  const int tid = threadIdx.x;
  const int w = tid >> 6, l = tid & 63;
  const int lr = l & 15, lg = l >> 4;
  const int n0 = blockIdx.x * 128, m0 = blockIdx.y * 128;
  const int wm = (w >> 1) * 64, wn = (w & 1) * 64;
  f32x4 acc[4][4] = {};
  const int srow = w * 16 + (l >> 2);
  const int scol = (l & 3) * 8;
  const unsigned short* ap0 = A + (size_t)(m0 + srow) * K + scol;
  const unsigned short* ap1 = ap0 + (size_t)64 * K;
  const unsigned short* bp0 = B + (size_t)(n0 + srow) * K + scol;
  const unsigned short* bp1 = bp0 + (size_t)64 * K;
  unsigned short* asl0 = As + w * 512;
  unsigned short* asl1 = As + 2048 + w * 512;
  unsigned short* bsl0 = Bs + w * 512;
  unsigned short* bsl1 = Bs + 2048 + w * 512;
  for (int k0 = 0; k0 < K; k0 += 32) {
    GL16(ap0 + k0, asl0);
    GL16(ap1 + k0, asl1);
    GL16(bp0 + k0, bsl0);
    GL16(bp1 + k0, bsl1);
    __syncthreads();
    bf16x8 af[4], bfr[4];
#pragma unroll
    for (int m = 0; m < 4; ++m) af[m] = *(const bf16x8*)(As + (wm + m * 16 + lr) * 32 + lg * 8);
#pragma unroll
    for (int n = 0; n < 4; ++n) bfr[n] = *(const bf16x8*)(Bs + (wn + n * 16 + lr) * 32 + lg * 8);
#pragma unroll
    for (int m = 0; m < 4; ++m)
#pragma unroll
      for (int n = 0; n < 4; ++n)
        acc[m][n] = __builtin_amdgcn_mfma_f32_16x16x32_bf16(af[m], bfr[n], acc[m][n], 0, 0, 0);
    __syncthreads();
  }
#pragma unroll
  for (int m = 0; m < 4; ++m) {
    int row = m0 + wm + m * 16 + lg * 4;
#pragma unroll
    for (int n = 0; n < 4; ++n) {
      int col = n0 + wn + n * 16 + lr;
#pragma unroll
      for (int r = 0; r < 4; ++r) {
        if (OUT_BF16)
          ((unsigned short*)Cout)[(size_t)(row + r) * N + col] = f2bf(acc[m][n][r]);
        else
          ((float*)Cout)[(size_t)(row + r) * N + col] = acc[m][n][r];
      }
    }
  }
}

// ---------------- flash attention v3: swapped-QK 32x32, GQA, causal ----------------
// grid = (32 qtiles, 32 heads), block = 128 (2 waves x 32 q-rows).
// qt = 31 - blockIdx.x: heaviest (most-tile) blocks dispatch first for packing.
__global__ __launch_bounds__(128) void attn3_kernel(const unsigned short* __restrict__ Q,
                                                    const unsigned short* __restrict__ K,
                                                    const unsigned short* __restrict__ VT,
                                                    const float* __restrict__ cost,
                                                    const float* __restrict__ sint,
                                                    const float* __restrict__ mask,
                                                    unsigned short* __restrict__ AO) {
  __shared__ __align__(16) unsigned short sm[2][8192];   // per buf: K 4096 elems | VT 4096 elems
  const int tid = threadIdx.x;
  const int w = tid >> 6, l = tid & 63;
  const int hi = l >> 5, l31 = l & 31;
  const int h = blockIdx.y, kvh = h >> 2;
  const int qt = 31 - blockIdx.x;        // big blocks first
  const int qrow = qt * 64 + w * 32 + l31;
  const float L2E = 1.44269504088896340736f;
  const int swz = (l & 7) << 4;
  const int hi16 = hi << 4;

  const int strow = l >> 3;
  const int scol = ((l & 7) ^ strow) * 8;    // pre-swizzled source column (elems)
  const unsigned short* kp0 = K + (size_t)((0 + w) * 8 + strow) * 512 + kvh * 64 + scol;
  const unsigned short* kp1 = K + (size_t)((2 + w) * 8 + strow) * 512 + kvh * 64 + scol;
  const unsigned short* kp2 = K + (size_t)((4 + w) * 8 + strow) * 512 + kvh * 64 + scol;
  const unsigned short* kp3 = K + (size_t)((6 + w) * 8 + strow) * 512 + kvh * 64 + scol;
  const unsigned short* vp0 = VT + (size_t)(kvh * 64 + (0 + w) * 8 + strow) * QLEN + scol;
  const unsigned short* vp1 = VT + (size_t)(kvh * 64 + (2 + w) * 8 + strow) * QLEN + scol;
  const unsigned short* vp2 = VT + (size_t)(kvh * 64 + (4 + w) * 8 + strow) * QLEN + scol;
  const unsigned short* vp3 = VT + (size_t)(kvh * 64 + (6 + w) * 8 + strow) * QLEN + scol;

#define STAGE(kt_, b_) do { \
    const size_t kko_ = (size_t)(kt_) * 32768; \
    const size_t vko_ = (size_t)(kt_) * 64; \
    unsigned short* smb_ = &sm[b_][0]; \
    GL16(kp0 + kko_, smb_ + (0 + w) * 512); \
    GL16(kp1 + kko_, smb_ + (2 + w) * 512); \
    GL16(kp2 + kko_, smb_ + (4 + w) * 512); \
    GL16(kp3 + kko_, smb_ + (6 + w) * 512); \
    GL16(vp0 + vko_, smb_ + 4096 + (0 + w) * 512); \
    GL16(vp1 + vko_, smb_ + 4096 + (2 + w) * 512); \
    GL16(vp2 + vko_, smb_ + 4096 + (4 + w) * 512); \
    GL16(vp3 + vko_, smb_ + 4096 + (6 + w) * 512); \
  } while (0)

  // ---- load Q (B-frag layout) + fused RoPE, scale 0.125 ----
  const unsigned short* qp = Q + (size_t)qrow * HIDDEN + h * HD + hi * 8;
  bf16x8 qv0 = *(const bf16x8*)qp;
  bf16x8 qv1 = *(const bf16x8*)(qp + 16);
  bf16x8 qv2 = *(const bf16x8*)(qp + 32);
  bf16x8 qv3 = *(const bf16x8*)(qp + 48);
  const float* cbp = cost + qrow * 32 + hi * 8;
  const float* sbp = sint + qrow * 32 + hi * 8;
  f32x4 ca0 = *(const f32x4*)cbp,        ca1 = *(const f32x4*)(cbp + 4);
  f32x4 cB0 = *(const f32x4*)(cbp + 16), cB1 = *(const f32x4*)(cbp + 20);
  f32x4 sa0 = *(const f32x4*)sbp,        sa1 = *(const f32x4*)(sbp + 4);
  f32x4 sB0 = *(const f32x4*)(sbp + 16), sB1 = *(const f32x4*)(sbp + 20);
  bf16x8 qr0, qr1, qr2, qr3;
#pragma unroll
  for (int j = 0; j < 8; ++j) {
    float cosA = j < 4 ? ca0[j] : ca1[j - 4];
    float sinA = j < 4 ? sa0[j] : sa1[j - 4];
    float cosB = j < 4 ? cB0[j] : cB1[j - 4];
    float sinB = j < 4 ? sB0[j] : sB1[j - 4];
    float x0 = bf2f((unsigned short)qv0[j]);
    float x1 = bf2f((unsigned short)qv1[j]);
    float x2 = bf2f((unsigned short)qv2[j]);
    float x3 = bf2f((unsigned short)qv3[j]);
    qr0[j] = (short)f2bf((x0 * cosA - x2 * sinA) * 0.125f);
    qr1[j] = (short)f2bf((x1 * cosB - x3 * sinB) * 0.125f);
    qr2[j] = (short)f2bf((x2 * cosA + x0 * sinA) * 0.125f);
    qr3[j] = (short)f2bf((x3 * cosB + x1 * sinB) * 0.125f);
  }

  f32x16 O0 = {}, O1 = {};
  float mR = -1e30f, sR = 0.f;
  int cur = 0;
  STAGE(0, 0);
  __syncthreads();

  for (int kt = 0; kt <= qt; ++kt) {
    if (kt < qt) STAGE(kt + 1, cur ^ 1);   // async prefetch into other buffer

    const char* Kc = (const char*)&sm[cur][0];
    const char* Vc = Kc + 8192;

    // ---- S^T = K * Q^T : C[key][q], col = l31 = q ----
    f32x16 sA = {}, sB = {};
#define KF(half, dc) (*(const bf16x8*)(Kc + (((half) * 32 + l31) << 7) + ((((dc) * 32 + hi16)) ^ swz)))
    sA = MFMA32(KF(0, 0), qr0, sA);
    sA = MFMA32(KF(0, 1), qr1, sA);
    sA = MFMA32(KF(0, 2), qr2, sA);
    sA = MFMA32(KF(0, 3), qr3, sA);
    sB = MFMA32(KF(1, 0), qr0, sB);
    sB = MFMA32(KF(1, 1), qr1, sB);
    sB = MFMA32(KF(1, 2), qr2, sB);
    sB = MFMA32(KF(1, 3), qr3, sB);
#undef KF

    if (kt == qt) {   // causal mask on diagonal tile
      const int wql = w * 32 + l31;
#pragma unroll
      for (int r = 0; r < 16; ++r) {
        int key = (r & 3) + 8 * (r >> 2) + 4 * hi;
        if (key > wql) sA[r] = -1e30f;
        if (32 + key > wql) sB[r] = -1e30f;
      }
    }

    // ---- online softmax: lane owns q-row qrow ----
    float mx = -1e30f;
#pragma unroll
    for (int r = 0; r < 16; ++r) mx = fmaxf(mx, sA[r]);
#pragma unroll
    for (int r = 0; r < 16; ++r) mx = fmaxf(mx, sB[r]);
    mx = fmaxf(mx, __shfl_xor(mx, 32));
    bool renorm = __any(mx - mR > 8.0f);   // defer-max (T13)
    if (renorm) {
      float mn = fmaxf(mR, mx);
      float sc = exp2f((mR - mn) * L2E);
      mR = mn;
      sR *= sc;
#pragma unroll
      for (int r = 0; r < 16; ++r) { O0[r] *= sc; O1[r] *= sc; }
    }
    const float mL = mR * L2E;
    float rs = 0.f;
#pragma unroll
    for (int r = 0; r < 16; ++r) { float p = exp2f(__builtin_fmaf(sA[r], L2E, -mL)); sA[r] = p; rs += p; }
#pragma unroll
    for (int r = 0; r < 16; ++r) { float p = exp2f(__builtin_fmaf(sB[r], L2E, -mL)); sB[r] = p; rs += p; }
    rs += __shfl_xor(rs, 32);
    sR += rs;

    // ---- P -> bf16 B-frags in-register (pack + half-exchange) ----
    bf16x8 pf[4];
#pragma unroll
    for (int kc = 0; kc < 4; ++kc) {
      const int r0 = (kc & 1) * 8;
      float p0, p1, p2, p3, p4, p5, p6, p7;
      if (kc & 2) { p0 = sB[r0+0]; p1 = sB[r0+1]; p2 = sB[r0+2]; p3 = sB[r0+3];
                    p4 = sB[r0+4]; p5 = sB[r0+5]; p6 = sB[r0+6]; p7 = sB[r0+7]; }
      else        { p0 = sA[r0+0]; p1 = sA[r0+1]; p2 = sA[r0+2]; p3 = sA[r0+3];
                    p4 = sA[r0+4]; p5 = sA[r0+5]; p6 = sA[r0+6]; p7 = sA[r0+7]; }
      unsigned a_ = pack_bf2(p0, p1);
      unsigned c_ = pack_bf2(p2, p3);
      unsigned b_ = pack_bf2(p4, p5);
      unsigned d_ = pack_bf2(p6, p7);
      unsigned ax = __shfl_xor(a_, 32), bx = __shfl_xor(b_, 32);
      unsigned cx = __shfl_xor(c_, 32), dx = __shfl_xor(d_, 32);
      union { unsigned u[4]; bf16x8 v; } uu;
      uu.u[0] = hi ? bx : a_;
      uu.u[1] = hi ? dx : c_;
      uu.u[2] = hi ? b_ : ax;
      uu.u[3] = hi ? d_ : cx;
      pf[kc] = uu.v;
    }

    // ---- PV: O^T += V^T * P^T ----
#define VF(n, kc) (*(const bf16x8*)(Vc + (((n) * 32 + l31) << 7) + ((((kc) * 32 + hi16)) ^ swz)))
    O0 = MFMA32(VF(0, 0), pf[0], O0);
    O1 = MFMA32(VF(1, 0), pf[0], O1);
    O0 = MFMA32(VF(0, 1), pf[1], O0);
    O1 = MFMA32(VF(1, 1), pf[1], O1);
    O0 = MFMA32(VF(0, 2), pf[2], O0);
    O1 = MFMA32(VF(1, 2), pf[2], O1);
    O0 = MFMA32(VF(0, 3), pf[3], O0);
    O1 = MFMA32(VF(1, 3), pf[3], O1);
#undef VF

    __syncthreads();
    cur ^= 1;
  }

  // ---- epilogue ----
  float msk = mask[(size_t)h * QLEN + qrow];
  float inv = msk / sR;
  unsigned short* aop = AO + (size_t)qrow * HIDDEN + h * HD;
#pragma unroll
  for (int rp = 0; rp < 8; ++rp) {
    int r = rp * 2;
    int d0 = (r & 3) + 8 * (r >> 2) + 4 * hi;
    *(unsigned*)(aop + d0)      = pack_bf2(O0[r] * inv, O0[r + 1] * inv);
    *(unsigned*)(aop + 32 + d0) = pack_bf2(O1[r] * inv, O1[r + 1] * inv);
  }
#undef STAGE
}

// ---------------- launcher ----------------
extern "C" void kernel_launch(void* const* d_in, const int* in_sizes, int n_in,
                              void* d_out, int out_size, void* d_ws, size_t ws_size,
                              hipStream_t stream) {
  const float* hs    = (const float*)d_in[0];
  const float* Wq    = (const float*)d_in[1];
  const float* Wk    = (const float*)d_in[2];
  const float* Wv    = (const float*)d_in[3];
  const float* Wo    = (const float*)d_in[4];
  const float* Wpred = (const float*)d_in[5];
  const int*   pid   = (const int*)d_in[6];
  float* out = (float*)d_out;

  unsigned short* hsb = (unsigned short*)d_ws;          // 4194304
  unsigned short* Wqb = hsb + 4194304;                  // 4194304
  unsigned short* Wkb = Wqb + 4194304;                  // 1048576
  unsigned short* Wvb = Wkb + 1048576;                  // 1048576
  unsigned short* Wob = Wvb + 1048576;                  // 4194304
  unsigned short* Qb  = Wob + 4194304;                  // 4194304
  unsigned short* Kb  = Qb  + 4194304;                  // 1048576
  unsigned short* Vb  = Kb  + 1048576;                  // 1048576
  unsigned short* AOb = Vb  + 1048576;                  // 4194304
  float* maskb = (float*)(AOb + 4194304);               // 65536 f32
  float* cost  = maskb + 65536;                         // 65536 f32
  float* sint  = cost + 65536;                          // 65536 f32
  unsigned short* VTb = hsb;   // hsb dead after projections; reuse for V^T

  cvt_kernel<<<4096, 256, 0, stream>>>(hs, hsb, 1048576);
  cvt_kernel<<<4096, 256, 0, stream>>>(Wq, Wqb, 1048576);
  cvt_kernel<<<1024, 256, 0, stream>>>(Wk, Wkb, 262144);
  cvt_kernel<<<1024, 256, 0, stream>>>(Wv, Wvb, 262144);
  cvt_kernel<<<4096, 256, 0, stream>>>(Wo, Wob, 1048576);

  rope_table_kernel<<<256, 256, 0, stream>>>(pid, cost, sint);
  headmask2_kernel<<<256, 256, 0, stream>>>(hs, Wpred, maskb);

  gemm2_kernel<true><<<dim3(16, 16), 256, 0, stream>>>(hsb, Wqb, Qb, 2048, 2048);
  gemm2_kernel<true><<<dim3(4, 16), 256, 0, stream>>>(hsb, Wkb, Kb, 512, 2048);
  gemm2_kernel<true><<<dim3(4, 16), 256, 0, stream>>>(hsb, Wvb, Vb, 512, 2048);

  rope_apply_kernel<<<2048, 256, 0, stream>>>(Kb, cost, sint, NKV, 1.0f, QLEN * NKV * 32);

  transpose_kernel<<<dim3(8, 32), 256, 0, stream>>>(Vb, VTb, QLEN, NKV * HD);

  attn3_kernel<<<dim3(32, 32), 128, 0, stream>>>(Qb, Kb, VTb, cost, sint, maskb, AOb);

  gemm2_kernel<false><<<dim3(16, 16), 256, 0, stream>>>(AOb, Wob, out, 2048, 2048);
}

// Round 6
// 427.377 us; speedup vs baseline: 1.2871x; 1.1076x over previous
//
#include <hip/hip_runtime.h>
#include <hip/hip_bf16.h>

#define HIDDEN 2048
#define NHEADS 32
#define NKV 8
#define HD 64
#define QLEN 2048

typedef short bf16x8 __attribute__((ext_vector_type(8)));
typedef float f32x4 __attribute__((ext_vector_type(4)));
typedef float f32x16 __attribute__((ext_vector_type(16)));

static __device__ __forceinline__ unsigned short f2bf(float f) {
  unsigned int u = __float_as_uint(f);
  u += 0x7fff + ((u >> 16) & 1);   // RNE
  return (unsigned short)(u >> 16);
}
static __device__ __forceinline__ float bf2f(unsigned short h) {
  return __uint_as_float(((unsigned int)h) << 16);
}
static __device__ __forceinline__ unsigned pack_bf2(float lo, float hi) {
  __hip_bfloat162 h2 = __float22bfloat162_rn(make_float2(lo, hi));  // x -> low 16
  unsigned u; __builtin_memcpy(&u, &h2, 4); return u;
}

#define GL16(gsrc, ldst) \
  __builtin_amdgcn_global_load_lds((const __attribute__((address_space(1))) unsigned int*)(gsrc), \
                                   (__attribute__((address_space(3))) unsigned int*)(ldst), 16, 0, 0)
#define MFMA32(a, b, c) __builtin_amdgcn_mfma_f32_32x32x16_bf16((a), (b), (c), 0, 0, 0)

// ---------------- f32 -> bf16 convert ----------------
__global__ void cvt_kernel(const float* __restrict__ in, unsigned short* __restrict__ out, int n4) {
  int i = blockIdx.x * blockDim.x + threadIdx.x;
  if (i >= n4) return;
  float4 v = ((const float4*)in)[i];
  ushort4 o;
  o.x = f2bf(v.x); o.y = f2bf(v.y); o.z = f2bf(v.z); o.w = f2bf(v.w);
  ((ushort4*)out)[i] = o;
}

// ---------------- RoPE cos/sin table: [pos][j], j=0..31 ----------------
__global__ void rope_table_kernel(const int* __restrict__ pid, float* __restrict__ cost, float* __restrict__ sint) {
  int t = blockIdx.x * blockDim.x + threadIdx.x;
  if (t >= QLEN * 32) return;
  int pos = t >> 5, j = t & 31;
  float p = (float)pid[pos];
  float inv = exp2f(-(float)j * 0.41524101187358740f);  // log2(10000)/32
  float f = p * inv;
  cost[t] = cosf(f);
  sint[t] = sinf(f);
}

// ---------------- head-mask stage A: transpose Wpred[32][2048] -> WpT[2048][32] ----------------
__global__ __launch_bounds__(256) void wpt_kernel(const float* __restrict__ Wpred, float* __restrict__ WpT) {
  int k = blockIdx.x * 256 + threadIdx.x;   // grid 8 -> 2048 threads
  float v[32];
#pragma unroll
  for (int h = 0; h < 32; ++h) v[h] = Wpred[(size_t)h * HIDDEN + k];   // coalesced across lanes
  float4* o = (float4*)(WpT + (size_t)k * 32);
#pragma unroll
  for (int j = 0; j < 8; ++j) o[j] = make_float4(v[4*j], v[4*j+1], v[4*j+2], v[4*j+3]);
}

// ---------------- head-mask stage B: partial dots, k split 4-way ----------------
// grid (256, 4), block 256 = 8 q x 32 h. WpT reads lane-coalesced, hs broadcast.
__global__ __launch_bounds__(256) void headmask_part_kernel(const float* __restrict__ hs,
                                                            const float* __restrict__ WpT,
                                                            double* __restrict__ part) {
  const int tid = threadIdx.x;
  const int ql = tid >> 5, hh = tid & 31;
  const int q = blockIdx.x * 8 + ql;
  const int ks = blockIdx.y;
  const float* hr = hs + (size_t)q * HIDDEN + ks * 512;
  const float* wp = WpT + (size_t)ks * 512 * 32 + hh;
  double a0 = 0.0, a1 = 0.0;
#pragma unroll 4
  for (int k = 0; k < 512; k += 4) {
    float4 hv = *(const float4*)(hr + k);
    float w0 = wp[(k + 0) * 32];
    float w1 = wp[(k + 1) * 32];
    float w2 = wp[(k + 2) * 32];
    float w3 = wp[(k + 3) * 32];
    a0 += (double)hv.x * (double)w0 + (double)hv.y * (double)w1;
    a1 += (double)hv.z * (double)w2 + (double)hv.w * (double)w3;
  }
  part[((size_t)ks * QLEN + q) * 32 + hh] = a0 + a1;
}

// ---------------- head-mask stage C: combine + rank (jax stable tie-break) ----------------
__global__ __launch_bounds__(256) void headmask_comb_kernel(const double* __restrict__ part,
                                                            float* __restrict__ mask) {
  __shared__ float lg[8][32];
  const int tid = threadIdx.x;
  const int ql = tid >> 5, hh = tid & 31;
  const int q = blockIdx.x * 8 + ql;
  double s = part[(size_t)q * 32 + hh]
           + part[((size_t)QLEN + q) * 32 + hh]
           + part[((size_t)2 * QLEN + q) * 32 + hh]
           + part[((size_t)3 * QLEN + q) * 32 + hh];
  float mine = (float)s;
  lg[ql][hh] = mine;
  __syncthreads();
  int rank = 0;
#pragma unroll
  for (int j = 0; j < NHEADS; ++j) {
    float oj = lg[ql][j];
    if (oj > mine || (oj == mine && j < hh)) ++rank;
  }
  mask[(size_t)hh * QLEN + q] = (rank < 16) ? 1.0f : 0.0f;
}

// ---------------- RoPE apply in-place (K only) ----------------
__global__ void rope_apply_kernel(unsigned short* __restrict__ X,
                                  const float* __restrict__ cost, const float* __restrict__ sint,
                                  int nh, float scale, int total) {
  int t = blockIdx.x * blockDim.x + threadIdx.x;
  if (t >= total) return;
  int j = t & 31;
  int h = (t >> 5) % nh;
  int pos = t / (32 * nh);
  size_t base = (size_t)pos * (nh * HD) + h * HD;
  float x0 = bf2f(X[base + j]);
  float x1 = bf2f(X[base + 32 + j]);
  float c = cost[pos * 32 + j];
  float s = sint[pos * 32 + j];
  X[base + j]      = f2bf((x0 * c - x1 * s) * scale);
  X[base + 32 + j] = f2bf((x1 * c + x0 * s) * scale);
}

// ---------------- bf16 tile transpose: out[C][R] = in[R][C]^T ----------------
__global__ __launch_bounds__(256) void transpose_kernel(const unsigned short* __restrict__ in,
                                                        unsigned short* __restrict__ out,
                                                        int R, int C) {
  __shared__ unsigned short t[64][72];
  int r0 = blockIdx.y * 64, c0 = blockIdx.x * 64;
  int tid = threadIdx.x;
  int rr = tid >> 3;
  int cc = (tid & 7) * 8;
#pragma unroll
  for (int c = 0; c < 2; ++c) {
    int row = rr + c * 32;
    *(bf16x8*)&t[row][cc] = *(const bf16x8*)(in + (size_t)(r0 + row) * C + c0 + cc);
  }
  __syncthreads();
#pragma unroll
  for (int c = 0; c < 2; ++c) {
    int oc = rr + c * 32;
    union { unsigned short s[8]; bf16x8 v; } o;
#pragma unroll
    for (int j = 0; j < 8; ++j) o.s[j] = t[cc + j][oc];
    *(bf16x8*)(out + (size_t)(c0 + oc) * R + r0 + cc) = o.v;
  }
}

// ---------------- bf16 GEMM (m97 structure): C[M,N] = A[M,K] * B[N,K]^T ----------------
template<bool OUT_BF16>
__global__ __launch_bounds__(256) void gemm2_kernel(const unsigned short* __restrict__ A,
                                                    const unsigned short* __restrict__ B,
                                                    void* __restrict__ Cout, int N, int K) {
  __shared__ __align__(16) unsigned short As[128 * 32];
  __shared__ __align__(16) unsigned short Bs[128 * 32];
  const int tid = threadIdx.x;
  const int w = tid >> 6, l = tid & 63;
  const int lr = l & 15, lg = l >> 4;
  const int n0 = blockIdx.x * 128, m0 = blockIdx.y * 128;
  const int wm = (w >> 1) * 64, wn = (w & 1) * 64;
  f32x4 acc[4][4] = {};
  const int srow = w * 16 + (l >> 2);
  const int scol = (l & 3) * 8;
  const unsigned short* ap0 = A + (size_t)(m0 + srow) * K + scol;
  const unsigned short* ap1 = ap0 + (size_t)64 * K;
  const unsigned short* bp0 = B + (size_t)(n0 + srow) * K + scol;
  const unsigned short* bp1 = bp0 + (size_t)64 * K;
  unsigned short* asl0 = As + w * 512;
  unsigned short* asl1 = As + 2048 + w * 512;
  unsigned short* bsl0 = Bs + w * 512;
  unsigned short* bsl1 = Bs + 2048 + w * 512;
  for (int k0 = 0; k0 < K; k0 += 32) {
    GL16(ap0 + k0, asl0);
    GL16(ap1 + k0, asl1);
    GL16(bp0 + k0, bsl0);
    GL16(bp1 + k0, bsl1);
    __syncthreads();
    bf16x8 af[4], bfr[4];
#pragma unroll
    for (int m = 0; m < 4; ++m) af[m] = *(const bf16x8*)(As + (wm + m * 16 + lr) * 32 + lg * 8);
#pragma unroll
    for (int n = 0; n < 4; ++n) bfr[n] = *(const bf16x8*)(Bs + (wn + n * 16 + lr) * 32 + lg * 8);
#pragma unroll
    for (int m = 0; m < 4; ++m)
#pragma unroll
      for (int n = 0; n < 4; ++n)
        acc[m][n] = __builtin_amdgcn_mfma_f32_16x16x32_bf16(af[m], bfr[n], acc[m][n], 0, 0, 0);
    __syncthreads();
  }
#pragma unroll
  for (int m = 0; m < 4; ++m) {
    int row = m0 + wm + m * 16 + lg * 4;
#pragma unroll
    for (int n = 0; n < 4; ++n) {
      int col = n0 + wn + n * 16 + lr;
#pragma unroll
      for (int r = 0; r < 4; ++r) {
        if (OUT_BF16)
          ((unsigned short*)Cout)[(size_t)(row + r) * N + col] = f2bf(acc[m][n][r]);
        else
          ((float*)Cout)[(size_t)(row + r) * N + col] = acc[m][n][r];
      }
    }
  }
}

// ---------------- flash attention v4: split-k chunks for load balance ----------------
// grid (48, 32): bx -> (qt, ch) statically, big chunks first. Chunk = <=16 k-tiles.
// qt<16: single chunk, final output. qt>=16: 2 chunks write (O,m,s) partials.
__global__ __launch_bounds__(128) void attn4_kernel(const unsigned short* __restrict__ Q,
                                                    const unsigned short* __restrict__ K,
                                                    const unsigned short* __restrict__ VT,
                                                    const float* __restrict__ cost,
                                                    const float* __restrict__ sint,
                                                    const float* __restrict__ mask,
                                                    unsigned short* __restrict__ AO,
                                                    float* __restrict__ Opart,
                                                    float2* __restrict__ msp) {
  __shared__ __align__(16) unsigned short sm[2][8192];   // per buf: K 4096 elems | VT 4096 elems
  const int tid = threadIdx.x;
  const int w = tid >> 6, l = tid & 63;
  const int hi = l >> 5, l31 = l & 31;
  const int h = blockIdx.y, kvh = h >> 2;
  const int bx = blockIdx.x;
  int qt, ch;
  if (bx < 16)      { qt = 16 + bx;  ch = 0; }   // 16-tile chunks
  else if (bx < 32) { qt = 47 - bx;  ch = 1; }   // sizes 16..1
  else              { qt = 47 - bx;  ch = 0; }   // sizes 16..1
  const int t0 = ch ? 16 : 0;
  const int t1 = ch ? qt : (qt < 15 ? qt : 15);
  const int qrow = qt * 64 + w * 32 + l31;
  const float L2E = 1.44269504088896340736f;
  const int swz = (l & 7) << 4;
  const int hi16 = hi << 4;

  const int strow = l >> 3;
  const int scol = ((l & 7) ^ strow) * 8;    // pre-swizzled source column (elems)
  const unsigned short* kp0 = K + (size_t)((0 + w) * 8 + strow) * 512 + kvh * 64 + scol;
  const unsigned short* kp1 = K + (size_t)((2 + w) * 8 + strow) * 512 + kvh * 64 + scol;
  const unsigned short* kp2 = K + (size_t)((4 + w) * 8 + strow) * 512 + kvh * 64 + scol;
  const unsigned short* kp3 = K + (size_t)((6 + w) * 8 + strow) * 512 + kvh * 64 + scol;
  const unsigned short* vp0 = VT + (size_t)(kvh * 64 + (0 + w) * 8 + strow) * QLEN + scol;
  const unsigned short* vp1 = VT + (size_t)(kvh * 64 + (2 + w) * 8 + strow) * QLEN + scol;
  const unsigned short* vp2 = VT + (size_t)(kvh * 64 + (4 + w) * 8 + strow) * QLEN + scol;
  const unsigned short* vp3 = VT + (size_t)(kvh * 64 + (6 + w) * 8 + strow) * QLEN + scol;

#define STAGE(kt_, b_) do { \
    const size_t kko_ = (size_t)(kt_) * 32768; \
    const size_t vko_ = (size_t)(kt_) * 64; \
    unsigned short* smb_ = &sm[b_][0]; \
    GL16(kp0 + kko_, smb_ + (0 + w) * 512); \
    GL16(kp1 + kko_, smb_ + (2 + w) * 512); \
    GL16(kp2 + kko_, smb_ + (4 + w) * 512); \
    GL16(kp3 + kko_, smb_ + (6 + w) * 512); \
    GL16(vp0 + vko_, smb_ + 4096 + (0 + w) * 512); \
    GL16(vp1 + vko_, smb_ + 4096 + (2 + w) * 512); \
    GL16(vp2 + vko_, smb_ + 4096 + (4 + w) * 512); \
    GL16(vp3 + vko_, smb_ + 4096 + (6 + w) * 512); \
  } while (0)

  // ---- load Q (B-frag layout) + fused RoPE, scale 0.125 ----
  const unsigned short* qp = Q + (size_t)qrow * HIDDEN + h * HD + hi * 8;
  bf16x8 qv0 = *(const bf16x8*)qp;
  bf16x8 qv1 = *(const bf16x8*)(qp + 16);
  bf16x8 qv2 = *(const bf16x8*)(qp + 32);
  bf16x8 qv3 = *(const bf16x8*)(qp + 48);
  const float* cbp = cost + qrow * 32 + hi * 8;
  const float* sbp = sint + qrow * 32 + hi * 8;
  f32x4 ca0 = *(const f32x4*)cbp,        ca1 = *(const f32x4*)(cbp + 4);
  f32x4 cB0 = *(const f32x4*)(cbp + 16), cB1 = *(const f32x4*)(cbp + 20);
  f32x4 sa0 = *(const f32x4*)sbp,        sa1 = *(const f32x4*)(sbp + 4);
  f32x4 sB0 = *(const f32x4*)(sbp + 16), sB1 = *(const f32x4*)(sbp + 20);
  bf16x8 qr0, qr1, qr2, qr3;
#pragma unroll
  for (int j = 0; j < 8; ++j) {
    float cosA = j < 4 ? ca0[j] : ca1[j - 4];
    float sinA = j < 4 ? sa0[j] : sa1[j - 4];
    float cosB = j < 4 ? cB0[j] : cB1[j - 4];
    float sinB = j < 4 ? sB0[j] : sB1[j - 4];
    float x0 = bf2f((unsigned short)qv0[j]);
    float x1 = bf2f((unsigned short)qv1[j]);
    float x2 = bf2f((unsigned short)qv2[j]);
    float x3 = bf2f((unsigned short)qv3[j]);
    qr0[j] = (short)f2bf((x0 * cosA - x2 * sinA) * 0.125f);
    qr1[j] = (short)f2bf((x1 * cosB - x3 * sinB) * 0.125f);
    qr2[j] = (short)f2bf((x2 * cosA + x0 * sinA) * 0.125f);
    qr3[j] = (short)f2bf((x3 * cosB + x1 * sinB) * 0.125f);
  }

  f32x16 O0 = {}, O1 = {};
  float mR = -1e30f, sR = 0.f;
  int cur = 0;
  STAGE(t0, 0);
  __syncthreads();

  for (int kt = t0; kt <= t1; ++kt) {
    if (kt < t1) STAGE(kt + 1, cur ^ 1);

    const char* Kc = (const char*)&sm[cur][0];
    const char* Vc = Kc + 8192;

    // ---- S^T = K * Q^T : C[key][q], col = l31 = q ----
    f32x16 sA = {}, sB = {};
#define KF(half, dc) (*(const bf16x8*)(Kc + (((half) * 32 + l31) << 7) + ((((dc) * 32 + hi16)) ^ swz)))
    sA = MFMA32(KF(0, 0), qr0, sA);
    sA = MFMA32(KF(0, 1), qr1, sA);
    sA = MFMA32(KF(0, 2), qr2, sA);
    sA = MFMA32(KF(0, 3), qr3, sA);
    sB = MFMA32(KF(1, 0), qr0, sB);
    sB = MFMA32(KF(1, 1), qr1, sB);
    sB = MFMA32(KF(1, 2), qr2, sB);
    sB = MFMA32(KF(1, 3), qr3, sB);
#undef KF

    if (kt == qt) {   // causal mask on diagonal tile
      const int wql = w * 32 + l31;
#pragma unroll
      for (int r = 0; r < 16; ++r) {
        int key = (r & 3) + 8 * (r >> 2) + 4 * hi;
        if (key > wql) sA[r] = -1e30f;
        if (32 + key > wql) sB[r] = -1e30f;
      }
    }

    // ---- online softmax: lane owns q-row qrow ----
    float mx = -1e30f;
#pragma unroll
    for (int r = 0; r < 16; ++r) mx = fmaxf(mx, sA[r]);
#pragma unroll
    for (int r = 0; r < 16; ++r) mx = fmaxf(mx, sB[r]);
    mx = fmaxf(mx, __shfl_xor(mx, 32));
    bool renorm = __any(mx - mR > 8.0f);   // defer-max (T13)
    if (renorm) {
      float mn = fmaxf(mR, mx);
      float sc = exp2f((mR - mn) * L2E);
      mR = mn;
      sR *= sc;
#pragma unroll
      for (int r = 0; r < 16; ++r) { O0[r] *= sc; O1[r] *= sc; }
    }
    const float mL = mR * L2E;
    float rs = 0.f;
#pragma unroll
    for (int r = 0; r < 16; ++r) { float p = exp2f(__builtin_fmaf(sA[r], L2E, -mL)); sA[r] = p; rs += p; }
#pragma unroll
    for (int r = 0; r < 16; ++r) { float p = exp2f(__builtin_fmaf(sB[r], L2E, -mL)); sB[r] = p; rs += p; }
    rs += __shfl_xor(rs, 32);
    sR += rs;

    // ---- P -> bf16 B-frags in-register (pack + half-exchange) ----
    bf16x8 pf[4];
#pragma unroll
    for (int kc = 0; kc < 4; ++kc) {
      const int r0 = (kc & 1) * 8;
      float p0, p1, p2, p3, p4, p5, p6, p7;
      if (kc & 2) { p0 = sB[r0+0]; p1 = sB[r0+1]; p2 = sB[r0+2]; p3 = sB[r0+3];
                    p4 = sB[r0+4]; p5 = sB[r0+5]; p6 = sB[r0+6]; p7 = sB[r0+7]; }
      else        { p0 = sA[r0+0]; p1 = sA[r0+1]; p2 = sA[r0+2]; p3 = sA[r0+3];
                    p4 = sA[r0+4]; p5 = sA[r0+5]; p6 = sA[r0+6]; p7 = sA[r0+7]; }
      unsigned a_ = pack_bf2(p0, p1);
      unsigned c_ = pack_bf2(p2, p3);
      unsigned b_ = pack_bf2(p4, p5);
      unsigned d_ = pack_bf2(p6, p7);
      unsigned ax = __shfl_xor(a_, 32), bx2 = __shfl_xor(b_, 32);
      unsigned cx = __shfl_xor(c_, 32), dx = __shfl_xor(d_, 32);
      union { unsigned u[4]; bf16x8 v; } uu;
      uu.u[0] = hi ? bx2 : a_;
      uu.u[1] = hi ? dx : c_;
      uu.u[2] = hi ? b_ : ax;
      uu.u[3] = hi ? d_ : cx;
      pf[kc] = uu.v;
    }

    // ---- PV: O^T += V^T * P^T ----
#define VF(n, kc) (*(const bf16x8*)(Vc + (((n) * 32 + l31) << 7) + ((((kc) * 32 + hi16)) ^ swz)))
    O0 = MFMA32(VF(0, 0), pf[0], O0);
    O1 = MFMA32(VF(1, 0), pf[0], O1);
    O0 = MFMA32(VF(0, 1), pf[1], O0);
    O1 = MFMA32(VF(1, 1), pf[1], O1);
    O0 = MFMA32(VF(0, 2), pf[2], O0);
    O1 = MFMA32(VF(1, 2), pf[2], O1);
    O0 = MFMA32(VF(0, 3), pf[3], O0);
    O1 = MFMA32(VF(1, 3), pf[3], O1);
#undef VF

    __syncthreads();
    cur ^= 1;
  }

  if (qt < 16) {
    // ---- final epilogue ----
    float msk = mask[(size_t)h * QLEN + qrow];
    float inv = msk / sR;
    unsigned short* aop = AO + (size_t)qrow * HIDDEN + h * HD;
#pragma unroll
    for (int rp = 0; rp < 8; ++rp) {
      int r = rp * 2;
      int d0 = (r & 3) + 8 * (r >> 2) + 4 * hi;
      *(unsigned*)(aop + d0)      = pack_bf2(O0[r] * inv, O0[r + 1] * inv);
      *(unsigned*)(aop + 32 + d0) = pack_bf2(O1[r] * inv, O1[r + 1] * inv);
    }
  } else {
    // ---- partial write: (O, m, s) ----
    const int slot = ((qt - 16) * 32 + h) * 2 + ch;
    float* Op = Opart + (size_t)slot * 4096;
    const int qloc = w * 32 + l31;
#pragma unroll
    for (int rp = 0; rp < 8; ++rp) {
      int r = rp * 2;
      int d0 = (r & 3) + 8 * (r >> 2) + 4 * hi;
      *(float2*)(Op + qloc * 64 + d0)      = make_float2(O0[r], O0[r + 1]);
      *(float2*)(Op + qloc * 64 + 32 + d0) = make_float2(O1[r], O1[r + 1]);
    }
    if (hi == 0) msp[(size_t)slot * 64 + qloc] = make_float2(mR, sR);
  }
#undef STAGE
}

// ---------------- attention combine: merge 2 chunks for qt>=16 ----------------
__global__ __launch_bounds__(256) void attn_comb_kernel(const float* __restrict__ Opart,
                                                        const float2* __restrict__ msp,
                                                        const float* __restrict__ mask,
                                                        unsigned short* __restrict__ AO) {
  const int qt = 16 + blockIdx.x;
  const int h = blockIdx.y;
  const int tid = threadIdx.x;
  const int q = tid >> 2;
  const int dseg = (tid & 3) * 16;
  const int slot0 = ((qt - 16) * 32 + h) * 2;
  const float L2E = 1.44269504088896340736f;
  float2 ms0 = msp[(size_t)slot0 * 64 + q];
  float2 ms1 = msp[(size_t)(slot0 + 1) * 64 + q];
  float mstar = fmaxf(ms0.x, ms1.x);
  float c0 = exp2f((ms0.x - mstar) * L2E);
  float c1 = exp2f((ms1.x - mstar) * L2E);
  float s = c0 * ms0.y + c1 * ms1.y;
  const int qrow = qt * 64 + q;
  float inv = mask[(size_t)h * QLEN + qrow] / s;
  const float* O0p = Opart + (size_t)slot0 * 4096 + q * 64;
  const float* O1p = Opart + (size_t)(slot0 + 1) * 4096 + q * 64;
  unsigned short* aop = AO + (size_t)qrow * HIDDEN + h * HD;
#pragma unroll
  for (int d = dseg; d < dseg + 16; d += 4) {
    float4 a = *(const float4*)(O0p + d);
    float4 b = *(const float4*)(O1p + d);
    *(unsigned*)(aop + d)     = pack_bf2((c0 * a.x + c1 * b.x) * inv, (c0 * a.y + c1 * b.y) * inv);
    *(unsigned*)(aop + d + 2) = pack_bf2((c0 * a.z + c1 * b.z) * inv, (c0 * a.w + c1 * b.w) * inv);
  }
}

// ---------------- launcher ----------------
extern "C" void kernel_launch(void* const* d_in, const int* in_sizes, int n_in,
                              void* d_out, int out_size, void* d_ws, size_t ws_size,
                              hipStream_t stream) {
  const float* hs    = (const float*)d_in[0];
  const float* Wq    = (const float*)d_in[1];
  const float* Wk    = (const float*)d_in[2];
  const float* Wv    = (const float*)d_in[3];
  const float* Wo    = (const float*)d_in[4];
  const float* Wpred = (const float*)d_in[5];
  const int*   pid   = (const int*)d_in[6];
  float* out = (float*)d_out;

  unsigned short* hsb = (unsigned short*)d_ws;          // 4194304
  unsigned short* Wqb = hsb + 4194304;                  // 4194304
  unsigned short* Wkb = Wqb + 4194304;                  // 1048576
  unsigned short* Wvb = Wkb + 1048576;                  // 1048576
  unsigned short* Wob = Wvb + 1048576;                  // 4194304
  unsigned short* Qb  = Wob + 4194304;                  // 4194304
  unsigned short* Kb  = Qb  + 4194304;                  // 1048576
  unsigned short* Vb  = Kb  + 1048576;                  // 1048576
  unsigned short* AOb = Vb  + 1048576;                  // 4194304
  float* maskb = (float*)(AOb + 4194304);               // 65536 f32
  float* cost  = maskb + 65536;                         // 65536 f32
  float* sint  = cost + 65536;                          // 65536 f32
  float* WpT   = sint + 65536;                          // 65536 f32
  double* hmp  = (double*)(WpT + 65536);                // 262144 f64 (2 MB)
  float* Opart = (float*)(hmp + 262144);                // 1024*4096 f32 (16 MB)
  float2* msp  = (float2*)(Opart + 4194304);            // 65536 float2 (512 KB)
  unsigned short* VTb = hsb;   // hsb dead after projections; reuse for V^T

  cvt_kernel<<<4096, 256, 0, stream>>>(hs, hsb, 1048576);
  cvt_kernel<<<4096, 256, 0, stream>>>(Wq, Wqb, 1048576);
  cvt_kernel<<<1024, 256, 0, stream>>>(Wk, Wkb, 262144);
  cvt_kernel<<<1024, 256, 0, stream>>>(Wv, Wvb, 262144);
  cvt_kernel<<<4096, 256, 0, stream>>>(Wo, Wob, 1048576);

  rope_table_kernel<<<256, 256, 0, stream>>>(pid, cost, sint);

  wpt_kernel<<<8, 256, 0, stream>>>(Wpred, WpT);
  headmask_part_kernel<<<dim3(256, 4), 256, 0, stream>>>(hs, WpT, hmp);
  headmask_comb_kernel<<<256, 256, 0, stream>>>(hmp, maskb);

  gemm2_kernel<true><<<dim3(16, 16), 256, 0, stream>>>(hsb, Wqb, Qb, 2048, 2048);
  gemm2_kernel<true><<<dim3(4, 16), 256, 0, stream>>>(hsb, Wkb, Kb, 512, 2048);
  gemm2_kernel<true><<<dim3(4, 16), 256, 0, stream>>>(hsb, Wvb, Vb, 512, 2048);

  rope_apply_kernel<<<2048, 256, 0, stream>>>(Kb, cost, sint, NKV, 1.0f, QLEN * NKV * 32);

  transpose_kernel<<<dim3(8, 32), 256, 0, stream>>>(Vb, VTb, QLEN, NKV * HD);

  attn4_kernel<<<dim3(48, 32), 128, 0, stream>>>(Qb, Kb, VTb, cost, sint, maskb, AOb, Opart, msp);
  attn_comb_kernel<<<dim3(16, 32), 256, 0, stream>>>(Opart, msp, maskb, AOb);

  gemm2_kernel<false><<<dim3(16, 16), 256, 0, stream>>>(AOb, Wob, out, 2048, 2048);
}

// Round 7
// 374.771 us; speedup vs baseline: 1.4678x; 1.1404x over previous
//
#include <hip/hip_runtime.h>
#include <hip/hip_bf16.h>

#define HIDDEN 2048
#define NHEADS 32
#define NKV 8
#define HD 64
#define QLEN 2048

typedef short bf16x8 __attribute__((ext_vector_type(8)));
typedef float f32x4 __attribute__((ext_vector_type(4)));
typedef float f32x16 __attribute__((ext_vector_type(16)));

static __device__ __forceinline__ unsigned short f2bf(float f) {
  unsigned int u = __float_as_uint(f);
  u += 0x7fff + ((u >> 16) & 1);   // RNE
  return (unsigned short)(u >> 16);
}
static __device__ __forceinline__ float bf2f(unsigned short h) {
  return __uint_as_float(((unsigned int)h) << 16);
}
static __device__ __forceinline__ unsigned pack_bf2(float lo, float hi) {
  __hip_bfloat162 h2 = __float22bfloat162_rn(make_float2(lo, hi));  // x -> low 16
  unsigned u; __builtin_memcpy(&u, &h2, 4); return u;
}

#define GL16(gsrc, ldst) \
  __builtin_amdgcn_global_load_lds((const __attribute__((address_space(1))) unsigned int*)(gsrc), \
                                   (__attribute__((address_space(3))) unsigned int*)(ldst), 16, 0, 0)
#define MFMA32(a, b, c) __builtin_amdgcn_mfma_f32_32x32x16_bf16((a), (b), (c), 0, 0, 0)

// ---------------- fused f32 -> bf16 convert for all 5 tensors ----------------
__global__ __launch_bounds__(256) void cvt_all_kernel(const float* __restrict__ p0, const float* __restrict__ p1,
                                                      const float* __restrict__ p2, const float* __restrict__ p3,
                                                      const float* __restrict__ p4,
                                                      unsigned short* __restrict__ q0, unsigned short* __restrict__ q1,
                                                      unsigned short* __restrict__ q2, unsigned short* __restrict__ q3,
                                                      unsigned short* __restrict__ q4) {
  const int n0 = 1048576, n1 = 2097152, n2 = 2359296, n3 = 2621440, n4 = 3670016;
  for (int t = blockIdx.x * 256 + threadIdx.x; t < n4; t += gridDim.x * 256) {
    const float4* src; unsigned short* dst; int off;
    if (t < n0)      { src = (const float4*)p0; dst = q0; off = t; }
    else if (t < n1) { src = (const float4*)p1; dst = q1; off = t - n0; }
    else if (t < n2) { src = (const float4*)p2; dst = q2; off = t - n1; }
    else if (t < n3) { src = (const float4*)p3; dst = q3; off = t - n2; }
    else             { src = (const float4*)p4; dst = q4; off = t - n3; }
    float4 v = src[off];
    ushort4 o;
    o.x = f2bf(v.x); o.y = f2bf(v.y); o.z = f2bf(v.z); o.w = f2bf(v.w);
    ((ushort4*)dst)[off] = o;
  }
}

// ---------------- RoPE cos/sin table: [pos][j], j=0..31 ----------------
__global__ void rope_table_kernel(const int* __restrict__ pid, float* __restrict__ cost, float* __restrict__ sint) {
  int t = blockIdx.x * blockDim.x + threadIdx.x;
  if (t >= QLEN * 32) return;
  int pos = t >> 5, j = t & 31;
  float p = (float)pid[pos];
  float inv = exp2f(-(float)j * 0.41524101187358740f);  // log2(10000)/32
  float f = p * inv;
  cost[t] = cosf(f);
  sint[t] = sinf(f);
}

// ---------------- head-mask stage A: transpose Wpred[32][2048] -> WpT[2048][32] ----------------
__global__ __launch_bounds__(256) void wpt_kernel(const float* __restrict__ Wpred, float* __restrict__ WpT) {
  int k = blockIdx.x * 256 + threadIdx.x;
  float v[32];
#pragma unroll
  for (int h = 0; h < 32; ++h) v[h] = Wpred[(size_t)h * HIDDEN + k];
  float4* o = (float4*)(WpT + (size_t)k * 32);
#pragma unroll
  for (int j = 0; j < 8; ++j) o[j] = make_float4(v[4*j], v[4*j+1], v[4*j+2], v[4*j+3]);
}

// ---------------- head-mask stage B: partial dots, k split 4-way ----------------
__global__ __launch_bounds__(256) void headmask_part_kernel(const float* __restrict__ hs,
                                                            const float* __restrict__ WpT,
                                                            double* __restrict__ part) {
  const int tid = threadIdx.x;
  const int ql = tid >> 5, hh = tid & 31;
  const int q = blockIdx.x * 8 + ql;
  const int ks = blockIdx.y;
  const float* hr = hs + (size_t)q * HIDDEN + ks * 512;
  const float* wp = WpT + (size_t)ks * 512 * 32 + hh;
  double a0 = 0.0, a1 = 0.0;
#pragma unroll 4
  for (int k = 0; k < 512; k += 4) {
    float4 hv = *(const float4*)(hr + k);
    float w0 = wp[(k + 0) * 32];
    float w1 = wp[(k + 1) * 32];
    float w2 = wp[(k + 2) * 32];
    float w3 = wp[(k + 3) * 32];
    a0 += (double)hv.x * (double)w0 + (double)hv.y * (double)w1;
    a1 += (double)hv.z * (double)w2 + (double)hv.w * (double)w3;
  }
  part[((size_t)ks * QLEN + q) * 32 + hh] = a0 + a1;
}

// ---------------- head-mask stage C: combine + rank (jax stable tie-break) ----------------
__global__ __launch_bounds__(256) void headmask_comb_kernel(const double* __restrict__ part,
                                                            float* __restrict__ mask) {
  __shared__ float lg[8][32];
  const int tid = threadIdx.x;
  const int ql = tid >> 5, hh = tid & 31;
  const int q = blockIdx.x * 8 + ql;
  double s = part[(size_t)q * 32 + hh]
           + part[((size_t)QLEN + q) * 32 + hh]
           + part[((size_t)2 * QLEN + q) * 32 + hh]
           + part[((size_t)3 * QLEN + q) * 32 + hh];
  float mine = (float)s;
  lg[ql][hh] = mine;
  __syncthreads();
  int rank = 0;
#pragma unroll
  for (int j = 0; j < NHEADS; ++j) {
    float oj = lg[ql][j];
    if (oj > mine || (oj == mine && j < hh)) ++rank;
  }
  mask[(size_t)hh * QLEN + q] = (rank < 16) ? 1.0f : 0.0f;
}

// ---------------- RoPE apply in-place (K in KV buffer), row stride param ----------------
__global__ void rope_apply_kernel(unsigned short* __restrict__ X,
                                  const float* __restrict__ cost, const float* __restrict__ sint,
                                  int nh, int rowstride, int total) {
  int t = blockIdx.x * blockDim.x + threadIdx.x;
  if (t >= total) return;
  int j = t & 31;
  int h = (t >> 5) % nh;
  int pos = t / (32 * nh);
  size_t base = (size_t)pos * rowstride + h * HD;
  float x0 = bf2f(X[base + j]);
  float x1 = bf2f(X[base + 32 + j]);
  float c = cost[pos * 32 + j];
  float s = sint[pos * 32 + j];
  X[base + j]      = f2bf(x0 * c - x1 * s);
  X[base + 32 + j] = f2bf(x1 * c + x0 * s);
}

// ---------------- bf16 tile transpose with input stride: out[C][R] = in^T ----------------
__global__ __launch_bounds__(256) void transpose_kernel(const unsigned short* __restrict__ in,
                                                        unsigned short* __restrict__ out,
                                                        int R, int C, int ldin) {
  __shared__ unsigned short t[64][72];
  int r0 = blockIdx.y * 64, c0 = blockIdx.x * 64;
  int tid = threadIdx.x;
  int rr = tid >> 3;
  int cc = (tid & 7) * 8;
#pragma unroll
  for (int c = 0; c < 2; ++c) {
    int row = rr + c * 32;
    *(bf16x8*)&t[row][cc] = *(const bf16x8*)(in + (size_t)(r0 + row) * ldin + c0 + cc);
  }
  __syncthreads();
#pragma unroll
  for (int c = 0; c < 2; ++c) {
    int oc = rr + c * 32;
    union { unsigned short s[8]; bf16x8 v; } o;
#pragma unroll
    for (int j = 0; j < 8; ++j) o.s[j] = t[cc + j][oc];
    *(bf16x8*)(out + (size_t)(c0 + oc) * R + r0 + cc) = o.v;
  }
}

// ---------------- bf16 GEMM (m97 structure): C[M,N] = A[M,K] * B[N,K]^T ----------------
template<bool OUT_BF16>
__global__ __launch_bounds__(256) void gemm2_kernel(const unsigned short* __restrict__ A,
                                                    const unsigned short* __restrict__ B,
                                                    void* __restrict__ Cout, int N, int K) {
  __shared__ __align__(16) unsigned short As[128 * 32];
  __shared__ __align__(16) unsigned short Bs[128 * 32];
  const int tid = threadIdx.x;
  const int w = tid >> 6, l = tid & 63;
  const int lr = l & 15, lg = l >> 4;
  const int n0 = blockIdx.x * 128, m0 = blockIdx.y * 128;
  const int wm = (w >> 1) * 64, wn = (w & 1) * 64;
  f32x4 acc[4][4] = {};
  const int srow = w * 16 + (l >> 2);
  const int scol = (l & 3) * 8;
  const unsigned short* ap0 = A + (size_t)(m0 + srow) * K + scol;
  const unsigned short* ap1 = ap0 + (size_t)64 * K;
  const unsigned short* bp0 = B + (size_t)(n0 + srow) * K + scol;
  const unsigned short* bp1 = bp0 + (size_t)64 * K;
  unsigned short* asl0 = As + w * 512;
  unsigned short* asl1 = As + 2048 + w * 512;
  unsigned short* bsl0 = Bs + w * 512;
  unsigned short* bsl1 = Bs + 2048 + w * 512;
  for (int k0 = 0; k0 < K; k0 += 32) {
    GL16(ap0 + k0, asl0);
    GL16(ap1 + k0, asl1);
    GL16(bp0 + k0, bsl0);
    GL16(bp1 + k0, bsl1);
    __syncthreads();
    bf16x8 af[4], bfr[4];
#pragma unroll
    for (int m = 0; m < 4; ++m) af[m] = *(const bf16x8*)(As + (wm + m * 16 + lr) * 32 + lg * 8);
#pragma unroll
    for (int n = 0; n < 4; ++n) bfr[n] = *(const bf16x8*)(Bs + (wn + n * 16 + lr) * 32 + lg * 8);
#pragma unroll
    for (int m = 0; m < 4; ++m)
#pragma unroll
      for (int n = 0; n < 4; ++n)
        acc[m][n] = __builtin_amdgcn_mfma_f32_16x16x32_bf16(af[m], bfr[n], acc[m][n], 0, 0, 0);
    __syncthreads();
  }
#pragma unroll
  for (int m = 0; m < 4; ++m) {
    int row = m0 + wm + m * 16 + lg * 4;
#pragma unroll
    for (int n = 0; n < 4; ++n) {
      int col = n0 + wn + n * 16 + lr;
#pragma unroll
      for (int r = 0; r < 4; ++r) {
        if (OUT_BF16)
          ((unsigned short*)Cout)[(size_t)(row + r) * N + col] = f2bf(acc[m][n][r]);
        else
          ((float*)Cout)[(size_t)(row + r) * N + col] = acc[m][n][r];
      }
    }
  }
}

// ---------------- flash attention v5: K via LDS dbuf, V direct from L2 ----------------
// grid (32 qtiles big-first, 32 heads), block 128 (2 waves x 32 q-rows).
// KV buffer: row stride 1024 (K cols 0-511). VT: [512 d][2048 keys].
// Q scaled by 0.125*log2(e): scores in log2 units, exp2 args are pure subtracts.
__global__ __launch_bounds__(128) void attn5_kernel(const unsigned short* __restrict__ Q,
                                                    const unsigned short* __restrict__ KV,
                                                    const unsigned short* __restrict__ VT,
                                                    const float* __restrict__ cost,
                                                    const float* __restrict__ sint,
                                                    const float* __restrict__ mask,
                                                    unsigned short* __restrict__ AO) {
  __shared__ __align__(16) unsigned short sm[2][4096];   // K tile dbuf only, 16 KB
  const int tid = threadIdx.x;
  const int w = tid >> 6, l = tid & 63;
  const int hi = l >> 5, l31 = l & 31;
  const int h = blockIdx.y, kvh = h >> 2;
  const int qt = 31 - blockIdx.x;        // big blocks first
  const int qrow = qt * 64 + w * 32 + l31;
  const int swz = (l & 7) << 4;
  const int hi16 = hi << 4;
  const float DEFER_T = 11.5415603f;     // 8 * log2(e)

  const int strow = l >> 3;
  const int scol = ((l & 7) ^ strow) * 8;    // pre-swizzled source column (elems)
  const unsigned short* kp0 = KV + (size_t)((0 + w) * 8 + strow) * 1024 + kvh * 64 + scol;
  const unsigned short* kp1 = KV + (size_t)((2 + w) * 8 + strow) * 1024 + kvh * 64 + scol;
  const unsigned short* kp2 = KV + (size_t)((4 + w) * 8 + strow) * 1024 + kvh * 64 + scol;
  const unsigned short* kp3 = KV + (size_t)((6 + w) * 8 + strow) * 1024 + kvh * 64 + scol;

#define STAGE(kt_, b_) do { \
    const size_t kko_ = (size_t)(kt_) * 65536; \
    unsigned short* smb_ = &sm[b_][0]; \
    GL16(kp0 + kko_, smb_ + (0 + w) * 512); \
    GL16(kp1 + kko_, smb_ + (2 + w) * 512); \
    GL16(kp2 + kko_, smb_ + (4 + w) * 512); \
    GL16(kp3 + kko_, smb_ + (6 + w) * 512); \
  } while (0)

  // ---- load Q (B-frag layout) + fused RoPE; scale folds 1/8 and log2(e) ----
  const float QSC = 0.125f * 1.44269504088896340736f;
  const unsigned short* qp = Q + (size_t)qrow * HIDDEN + h * HD + hi * 8;
  bf16x8 qv0 = *(const bf16x8*)qp;
  bf16x8 qv1 = *(const bf16x8*)(qp + 16);
  bf16x8 qv2 = *(const bf16x8*)(qp + 32);
  bf16x8 qv3 = *(const bf16x8*)(qp + 48);
  const float* cbp = cost + qrow * 32 + hi * 8;
  const float* sbp = sint + qrow * 32 + hi * 8;
  f32x4 ca0 = *(const f32x4*)cbp,        ca1 = *(const f32x4*)(cbp + 4);
  f32x4 cB0 = *(const f32x4*)(cbp + 16), cB1 = *(const f32x4*)(cbp + 20);
  f32x4 sa0 = *(const f32x4*)sbp,        sa1 = *(const f32x4*)(sbp + 4);
  f32x4 sB0 = *(const f32x4*)(sbp + 16), sB1 = *(const f32x4*)(sbp + 20);
  bf16x8 qr0, qr1, qr2, qr3;
#pragma unroll
  for (int j = 0; j < 8; ++j) {
    float cosA = j < 4 ? ca0[j] : ca1[j - 4];
    float sinA = j < 4 ? sa0[j] : sa1[j - 4];
    float cosB = j < 4 ? cB0[j] : cB1[j - 4];
    float sinB = j < 4 ? sB0[j] : sB1[j - 4];
    float x0 = bf2f((unsigned short)qv0[j]);
    float x1 = bf2f((unsigned short)qv1[j]);
    float x2 = bf2f((unsigned short)qv2[j]);
    float x3 = bf2f((unsigned short)qv3[j]);
    qr0[j] = (short)f2bf((x0 * cosA - x2 * sinA) * QSC);
    qr1[j] = (short)f2bf((x1 * cosB - x3 * sinB) * QSC);
    qr2[j] = (short)f2bf((x2 * cosA + x0 * sinA) * QSC);
    qr3[j] = (short)f2bf((x3 * cosB + x1 * sinB) * QSC);
  }

  f32x16 O0 = {}, O1 = {};
  float mR = -1e30f, sR = 0.f;
  int cur = 0;
  STAGE(0, 0);
  __syncthreads();

  for (int kt = 0; kt <= qt; ++kt) {
    if (kt < qt) STAGE(kt + 1, cur ^ 1);

    const char* Kc = (const char*)&sm[cur][0];

    // ---- S^T = K * Q^T : C[key][q], col = l31 = q ----
    f32x16 sA = {}, sB = {};
#define KF(half, dc) (*(const bf16x8*)(Kc + (((half) * 32 + l31) << 7) + ((((dc) * 32 + hi16)) ^ swz)))
    sA = MFMA32(KF(0, 0), qr0, sA);
    sA = MFMA32(KF(0, 1), qr1, sA);
    sA = MFMA32(KF(0, 2), qr2, sA);
    sA = MFMA32(KF(0, 3), qr3, sA);
    sB = MFMA32(KF(1, 0), qr0, sB);
    sB = MFMA32(KF(1, 1), qr1, sB);
    sB = MFMA32(KF(1, 2), qr2, sB);
    sB = MFMA32(KF(1, 3), qr3, sB);
#undef KF

    // ---- V^T fragments direct from global (L2-resident); latency hides under softmax ----
    bf16x8 vf[2][4];
#pragma unroll
    for (int n = 0; n < 2; ++n)
#pragma unroll
      for (int kc = 0; kc < 4; ++kc)
        vf[n][kc] = *(const bf16x8*)(VT + (size_t)(kvh * 64 + n * 32 + l31) * QLEN
                                        + kt * 64 + kc * 16 + hi * 8);

    if (kt == qt) {   // causal mask on diagonal tile
      const int wql = w * 32 + l31;
#pragma unroll
      for (int r = 0; r < 16; ++r) {
        int key = (r & 3) + 8 * (r >> 2) + 4 * hi;
        if (key > wql) sA[r] = -1e30f;
        if (32 + key > wql) sB[r] = -1e30f;
      }
    }

    // ---- online softmax, tree reductions (scores already in log2 units) ----
#define MAX8(v, o) fmaxf(fmaxf(fmaxf(v[o], v[o+1]), fmaxf(v[o+2], v[o+3])), \
                         fmaxf(fmaxf(v[o+4], v[o+5]), fmaxf(v[o+6], v[o+7])))
    float mx = fmaxf(fmaxf(MAX8(sA, 0), MAX8(sA, 8)), fmaxf(MAX8(sB, 0), MAX8(sB, 8)));
#undef MAX8
    mx = fmaxf(mx, __shfl_xor(mx, 32));
    bool renorm = __any(mx - mR > DEFER_T);
    if (renorm) {
      float mn = fmaxf(mR, mx);
      float sc = exp2f(mR - mn);
      mR = mn;
      sR *= sc;
#pragma unroll
      for (int r = 0; r < 16; ++r) { O0[r] *= sc; O1[r] *= sc; }
    }
#pragma unroll
    for (int r = 0; r < 16; ++r) sA[r] = exp2f(sA[r] - mR);
#pragma unroll
    for (int r = 0; r < 16; ++r) sB[r] = exp2f(sB[r] - mR);
#define SUM8(v, o) (((v[o] + v[o+1]) + (v[o+2] + v[o+3])) + ((v[o+4] + v[o+5]) + (v[o+6] + v[o+7])))
    float rs = (SUM8(sA, 0) + SUM8(sA, 8)) + (SUM8(sB, 0) + SUM8(sB, 8));
#undef SUM8
    rs += __shfl_xor(rs, 32);
    sR += rs;

    // ---- P -> bf16 B-frags in-register (pack + half-exchange) ----
    bf16x8 pf[4];
#pragma unroll
    for (int kc = 0; kc < 4; ++kc) {
      const int r0 = (kc & 1) * 8;
      float p0, p1, p2, p3, p4, p5, p6, p7;
      if (kc & 2) { p0 = sB[r0+0]; p1 = sB[r0+1]; p2 = sB[r0+2]; p3 = sB[r0+3];
                    p4 = sB[r0+4]; p5 = sB[r0+5]; p6 = sB[r0+6]; p7 = sB[r0+7]; }
      else        { p0 = sA[r0+0]; p1 = sA[r0+1]; p2 = sA[r0+2]; p3 = sA[r0+3];
                    p4 = sA[r0+4]; p5 = sA[r0+5]; p6 = sA[r0+6]; p7 = sA[r0+7]; }
      unsigned a_ = pack_bf2(p0, p1);
      unsigned c_ = pack_bf2(p2, p3);
      unsigned b_ = pack_bf2(p4, p5);
      unsigned d_ = pack_bf2(p6, p7);
      unsigned ax = __shfl_xor(a_, 32), bx2 = __shfl_xor(b_, 32);
      unsigned cx = __shfl_xor(c_, 32), dx = __shfl_xor(d_, 32);
      union { unsigned u[4]; bf16x8 v; } uu;
      uu.u[0] = hi ? bx2 : a_;
      uu.u[1] = hi ? dx : c_;
      uu.u[2] = hi ? b_ : ax;
      uu.u[3] = hi ? d_ : cx;
      pf[kc] = uu.v;
    }

    // ---- PV: O^T += V^T * P^T ----
    O0 = MFMA32(vf[0][0], pf[0], O0);
    O1 = MFMA32(vf[1][0], pf[0], O1);
    O0 = MFMA32(vf[0][1], pf[1], O0);
    O1 = MFMA32(vf[1][1], pf[1], O1);
    O0 = MFMA32(vf[0][2], pf[2], O0);
    O1 = MFMA32(vf[1][2], pf[2], O1);
    O0 = MFMA32(vf[0][3], pf[3], O0);
    O1 = MFMA32(vf[1][3], pf[3], O1);

    __syncthreads();
    cur ^= 1;
  }

  // ---- epilogue ----
  float msk = mask[(size_t)h * QLEN + qrow];
  float inv = msk / sR;
  unsigned short* aop = AO + (size_t)qrow * HIDDEN + h * HD;
#pragma unroll
  for (int rp = 0; rp < 8; ++rp) {
    int r = rp * 2;
    int d0 = (r & 3) + 8 * (r >> 2) + 4 * hi;
    *(unsigned*)(aop + d0)      = pack_bf2(O0[r] * inv, O0[r + 1] * inv);
    *(unsigned*)(aop + 32 + d0) = pack_bf2(O1[r] * inv, O1[r + 1] * inv);
  }
#undef STAGE
}

// ---------------- launcher ----------------
extern "C" void kernel_launch(void* const* d_in, const int* in_sizes, int n_in,
                              void* d_out, int out_size, void* d_ws, size_t ws_size,
                              hipStream_t stream) {
  const float* hs    = (const float*)d_in[0];
  const float* Wq    = (const float*)d_in[1];
  const float* Wk    = (const float*)d_in[2];
  const float* Wv    = (const float*)d_in[3];
  const float* Wo    = (const float*)d_in[4];
  const float* Wpred = (const float*)d_in[5];
  const int*   pid   = (const int*)d_in[6];
  float* out = (float*)d_out;

  unsigned short* hsb = (unsigned short*)d_ws;          // 4194304
  unsigned short* Wqb = hsb + 4194304;                  // 4194304
  unsigned short* Wkb = Wqb + 4194304;                  // 1048576 (contiguous with Wvb)
  unsigned short* Wvb = Wkb + 1048576;                  // 1048576
  unsigned short* Wob = Wvb + 1048576;                  // 4194304
  unsigned short* Qb  = Wob + 4194304;                  // 4194304
  unsigned short* KVb = Qb  + 4194304;                  // 2097152 ([2048][1024]: K cols 0-511, V cols 512-1023)
  unsigned short* AOb = KVb + 2097152;                  // 4194304
  float* maskb = (float*)(AOb + 4194304);               // 65536 f32
  float* cost  = maskb + 65536;                         // 65536 f32
  float* sint  = cost + 65536;                          // 65536 f32
  float* WpT   = sint + 65536;                          // 65536 f32
  double* hmp  = (double*)(WpT + 65536);                // 262144 f64
  unsigned short* VTb = hsb;   // hsb dead after projections; reuse for V^T [512][2048]

  cvt_all_kernel<<<2048, 256, 0, stream>>>(hs, Wq, Wk, Wv, Wo, hsb, Wqb, Wkb, Wvb, Wob);

  rope_table_kernel<<<256, 256, 0, stream>>>(pid, cost, sint);

  wpt_kernel<<<8, 256, 0, stream>>>(Wpred, WpT);
  headmask_part_kernel<<<dim3(256, 4), 256, 0, stream>>>(hs, WpT, hmp);
  headmask_comb_kernel<<<256, 256, 0, stream>>>(hmp, maskb);

  gemm2_kernel<true><<<dim3(16, 16), 256, 0, stream>>>(hsb, Wqb, Qb, 2048, 2048);
  gemm2_kernel<true><<<dim3(8, 16), 256, 0, stream>>>(hsb, Wkb, KVb, 1024, 2048);  // K|V fused

  rope_apply_kernel<<<2048, 256, 0, stream>>>(KVb, cost, sint, NKV, 1024, QLEN * NKV * 32);

  transpose_kernel<<<dim3(8, 32), 256, 0, stream>>>(KVb + 512, VTb, QLEN, 512, 1024);

  attn5_kernel<<<dim3(32, 32), 128, 0, stream>>>(Qb, KVb, VTb, cost, sint, maskb, AOb);

  gemm2_kernel<false><<<dim3(16, 16), 256, 0, stream>>>(AOb, Wob, out, 2048, 2048);
}

// Round 8
// 327.850 us; speedup vs baseline: 1.6779x; 1.1431x over previous
//
#include <hip/hip_runtime.h>
#include <hip/hip_bf16.h>

#define HIDDEN 2048
#define NHEADS 32
#define NKV 8
#define HD 64
#define QLEN 2048

typedef short bf16x8 __attribute__((ext_vector_type(8)));
typedef float f32x4 __attribute__((ext_vector_type(4)));
typedef float f32x16 __attribute__((ext_vector_type(16)));

static __device__ __forceinline__ unsigned short f2bf(float f) {
  unsigned int u = __float_as_uint(f);
  u += 0x7fff + ((u >> 16) & 1);   // RNE
  return (unsigned short)(u >> 16);
}
static __device__ __forceinline__ float bf2f(unsigned short h) {
  return __uint_as_float(((unsigned int)h) << 16);
}
static __device__ __forceinline__ unsigned pack_bf2(float lo, float hi) {
  __hip_bfloat162 h2 = __float22bfloat162_rn(make_float2(lo, hi));  // x -> low 16
  unsigned u; __builtin_memcpy(&u, &h2, 4); return u;
}

#define GL16(gsrc, ldst) \
  __builtin_amdgcn_global_load_lds((const __attribute__((address_space(1))) unsigned int*)(gsrc), \
                                   (__attribute__((address_space(3))) unsigned int*)(ldst), 16, 0, 0)
#define MFMA32(a, b, c) __builtin_amdgcn_mfma_f32_32x32x16_bf16((a), (b), (c), 0, 0, 0)

// ---------------- fused f32 -> bf16 convert for all 5 tensors ----------------
__global__ __launch_bounds__(256) void cvt_all_kernel(const float* __restrict__ p0, const float* __restrict__ p1,
                                                      const float* __restrict__ p2, const float* __restrict__ p3,
                                                      const float* __restrict__ p4,
                                                      unsigned short* __restrict__ q0, unsigned short* __restrict__ q1,
                                                      unsigned short* __restrict__ q2, unsigned short* __restrict__ q3,
                                                      unsigned short* __restrict__ q4) {
  const int n0 = 1048576, n1 = 2097152, n2 = 2359296, n3 = 2621440, n4 = 3670016;
  for (int t = blockIdx.x * 256 + threadIdx.x; t < n4; t += gridDim.x * 256) {
    const float4* src; unsigned short* dst; int off;
    if (t < n0)      { src = (const float4*)p0; dst = q0; off = t; }
    else if (t < n1) { src = (const float4*)p1; dst = q1; off = t - n0; }
    else if (t < n2) { src = (const float4*)p2; dst = q2; off = t - n1; }
    else if (t < n3) { src = (const float4*)p3; dst = q3; off = t - n2; }
    else             { src = (const float4*)p4; dst = q4; off = t - n3; }
    float4 v = src[off];
    ushort4 o;
    o.x = f2bf(v.x); o.y = f2bf(v.y); o.z = f2bf(v.z); o.w = f2bf(v.w);
    ((ushort4*)dst)[off] = o;
  }
}

// ---------------- RoPE cos/sin table: [pos][j], j=0..31 ----------------
__global__ void rope_table_kernel(const int* __restrict__ pid, float* __restrict__ cost, float* __restrict__ sint) {
  int t = blockIdx.x * blockDim.x + threadIdx.x;
  if (t >= QLEN * 32) return;
  int pos = t >> 5, j = t & 31;
  float p = (float)pid[pos];
  float inv = exp2f(-(float)j * 0.41524101187358740f);  // log2(10000)/32
  float f = p * inv;
  cost[t] = cosf(f);
  sint[t] = sinf(f);
}

// ---------------- head-mask stage A: transpose Wpred[32][2048] -> WpT[2048][32] ----------------
__global__ __launch_bounds__(256) void wpt_kernel(const float* __restrict__ Wpred, float* __restrict__ WpT) {
  int k = blockIdx.x * 256 + threadIdx.x;
  float v[32];
#pragma unroll
  for (int h = 0; h < 32; ++h) v[h] = Wpred[(size_t)h * HIDDEN + k];
  float4* o = (float4*)(WpT + (size_t)k * 32);
#pragma unroll
  for (int j = 0; j < 8; ++j) o[j] = make_float4(v[4*j], v[4*j+1], v[4*j+2], v[4*j+3]);
}

// ---------------- head-mask stage B: partial dots, k split 4-way ----------------
__global__ __launch_bounds__(256) void headmask_part_kernel(const float* __restrict__ hs,
                                                            const float* __restrict__ WpT,
                                                            double* __restrict__ part) {
  const int tid = threadIdx.x;
  const int ql = tid >> 5, hh = tid & 31;
  const int q = blockIdx.x * 8 + ql;
  const int ks = blockIdx.y;
  const float* hr = hs + (size_t)q * HIDDEN + ks * 512;
  const float* wp = WpT + (size_t)ks * 512 * 32 + hh;
  double a0 = 0.0, a1 = 0.0;
#pragma unroll 4
  for (int k = 0; k < 512; k += 4) {
    float4 hv = *(const float4*)(hr + k);
    float w0 = wp[(k + 0) * 32];
    float w1 = wp[(k + 1) * 32];
    float w2 = wp[(k + 2) * 32];
    float w3 = wp[(k + 3) * 32];
    a0 += (double)hv.x * (double)w0 + (double)hv.y * (double)w1;
    a1 += (double)hv.z * (double)w2 + (double)hv.w * (double)w3;
  }
  part[((size_t)ks * QLEN + q) * 32 + hh] = a0 + a1;
}

// ---------------- head-mask stage C: combine + rank (jax stable tie-break) ----------------
__global__ __launch_bounds__(256) void headmask_comb_kernel(const double* __restrict__ part,
                                                            float* __restrict__ mask) {
  __shared__ float lg[8][32];
  const int tid = threadIdx.x;
  const int ql = tid >> 5, hh = tid & 31;
  const int q = blockIdx.x * 8 + ql;
  double s = part[(size_t)q * 32 + hh]
           + part[((size_t)QLEN + q) * 32 + hh]
           + part[((size_t)2 * QLEN + q) * 32 + hh]
           + part[((size_t)3 * QLEN + q) * 32 + hh];
  float mine = (float)s;
  lg[ql][hh] = mine;
  __syncthreads();
  int rank = 0;
#pragma unroll
  for (int j = 0; j < NHEADS; ++j) {
    float oj = lg[ql][j];
    if (oj > mine || (oj == mine && j < hh)) ++rank;
  }
  mask[(size_t)hh * QLEN + q] = (rank < 16) ? 1.0f : 0.0f;
}

// ---------------- RoPE apply in-place (K in KV buffer), row stride param ----------------
__global__ void rope_apply_kernel(unsigned short* __restrict__ X,
                                  const float* __restrict__ cost, const float* __restrict__ sint,
                                  int nh, int rowstride, int total) {
  int t = blockIdx.x * blockDim.x + threadIdx.x;
  if (t >= total) return;
  int j = t & 31;
  int h = (t >> 5) % nh;
  int pos = t / (32 * nh);
  size_t base = (size_t)pos * rowstride + h * HD;
  float x0 = bf2f(X[base + j]);
  float x1 = bf2f(X[base + 32 + j]);
  float c = cost[pos * 32 + j];
  float s = sint[pos * 32 + j];
  X[base + j]      = f2bf(x0 * c - x1 * s);
  X[base + 32 + j] = f2bf(x1 * c + x0 * s);
}

// ---------------- bf16 tile transpose with input stride: out[C][R] = in^T ----------------
__global__ __launch_bounds__(256) void transpose_kernel(const unsigned short* __restrict__ in,
                                                        unsigned short* __restrict__ out,
                                                        int R, int C, int ldin) {
  __shared__ unsigned short t[64][72];
  int r0 = blockIdx.y * 64, c0 = blockIdx.x * 64;
  int tid = threadIdx.x;
  int rr = tid >> 3;
  int cc = (tid & 7) * 8;
#pragma unroll
  for (int c = 0; c < 2; ++c) {
    int row = rr + c * 32;
    *(bf16x8*)&t[row][cc] = *(const bf16x8*)(in + (size_t)(r0 + row) * ldin + c0 + cc);
  }
  __syncthreads();
#pragma unroll
  for (int c = 0; c < 2; ++c) {
    int oc = rr + c * 32;
    union { unsigned short s[8]; bf16x8 v; } o;
#pragma unroll
    for (int j = 0; j < 8; ++j) o.s[j] = t[cc + j][oc];
    *(bf16x8*)(out + (size_t)(c0 + oc) * R + r0 + cc) = o.v;
  }
}

// ---------------- fused QKV GEMM: B rows = [Wq(2048) | Wk(512) | Wv(512)] ----------------
// C cols <2048 -> Qb[row][2048]; cols >=2048 -> KVb[row][1024]. grid (24,16).
__global__ __launch_bounds__(256) void gemm_qkv_kernel(const unsigned short* __restrict__ A,
                                                       const unsigned short* __restrict__ B,
                                                       unsigned short* __restrict__ Qo,
                                                       unsigned short* __restrict__ KVo) {
  const int K = 2048;
  __shared__ __align__(16) unsigned short As[128 * 32];
  __shared__ __align__(16) unsigned short Bs[128 * 32];
  const int tid = threadIdx.x;
  const int w = tid >> 6, l = tid & 63;
  const int lr = l & 15, lg = l >> 4;
  const int n0 = blockIdx.x * 128, m0 = blockIdx.y * 128;
  const int wm = (w >> 1) * 64, wn = (w & 1) * 64;
  f32x4 acc[4][4] = {};
  const int srow = w * 16 + (l >> 2);
  const int scol = (l & 3) * 8;
  const unsigned short* ap0 = A + (size_t)(m0 + srow) * K + scol;
  const unsigned short* ap1 = ap0 + (size_t)64 * K;
  const unsigned short* bp0 = B + (size_t)(n0 + srow) * K + scol;
  const unsigned short* bp1 = bp0 + (size_t)64 * K;
  unsigned short* asl0 = As + w * 512;
  unsigned short* asl1 = As + 2048 + w * 512;
  unsigned short* bsl0 = Bs + w * 512;
  unsigned short* bsl1 = Bs + 2048 + w * 512;
  for (int k0 = 0; k0 < K; k0 += 32) {
    GL16(ap0 + k0, asl0);
    GL16(ap1 + k0, asl1);
    GL16(bp0 + k0, bsl0);
    GL16(bp1 + k0, bsl1);
    __syncthreads();
    bf16x8 af[4], bfr[4];
#pragma unroll
    for (int m = 0; m < 4; ++m) af[m] = *(const bf16x8*)(As + (wm + m * 16 + lr) * 32 + lg * 8);
#pragma unroll
    for (int n = 0; n < 4; ++n) bfr[n] = *(const bf16x8*)(Bs + (wn + n * 16 + lr) * 32 + lg * 8);
#pragma unroll
    for (int m = 0; m < 4; ++m)
#pragma unroll
      for (int n = 0; n < 4; ++n)
        acc[m][n] = __builtin_amdgcn_mfma_f32_16x16x32_bf16(af[m], bfr[n], acc[m][n], 0, 0, 0);
    __syncthreads();
  }
  unsigned short* Cp;
  int ldc, cb;
  if (n0 < 2048) { Cp = Qo;  ldc = 2048; cb = n0; }
  else           { Cp = KVo; ldc = 1024; cb = n0 - 2048; }
#pragma unroll
  for (int m = 0; m < 4; ++m) {
    int row = m0 + wm + m * 16 + lg * 4;
#pragma unroll
    for (int n = 0; n < 4; ++n) {
      int col = cb + wn + n * 16 + lr;
#pragma unroll
      for (int r = 0; r < 4; ++r)
        Cp[(size_t)(row + r) * ldc + col] = f2bf(acc[m][n][r]);
    }
  }
}

// ---------------- bf16 GEMM (m97 structure): C[M,N] = A[M,K] * B[N,K]^T ----------------
template<bool OUT_BF16>
__global__ __launch_bounds__(256) void gemm2_kernel(const unsigned short* __restrict__ A,
                                                    const unsigned short* __restrict__ B,
                                                    void* __restrict__ Cout, int N, int K) {
  __shared__ __align__(16) unsigned short As[128 * 32];
  __shared__ __align__(16) unsigned short Bs[128 * 32];
  const int tid = threadIdx.x;
  const int w = tid >> 6, l = tid & 63;
  const int lr = l & 15, lg = l >> 4;
  const int n0 = blockIdx.x * 128, m0 = blockIdx.y * 128;
  const int wm = (w >> 1) * 64, wn = (w & 1) * 64;
  f32x4 acc[4][4] = {};
  const int srow = w * 16 + (l >> 2);
  const int scol = (l & 3) * 8;
  const unsigned short* ap0 = A + (size_t)(m0 + srow) * K + scol;
  const unsigned short* ap1 = ap0 + (size_t)64 * K;
  const unsigned short* bp0 = B + (size_t)(n0 + srow) * K + scol;
  const unsigned short* bp1 = bp0 + (size_t)64 * K;
  unsigned short* asl0 = As + w * 512;
  unsigned short* asl1 = As + 2048 + w * 512;
  unsigned short* bsl0 = Bs + w * 512;
  unsigned short* bsl1 = Bs + 2048 + w * 512;
  for (int k0 = 0; k0 < K; k0 += 32) {
    GL16(ap0 + k0, asl0);
    GL16(ap1 + k0, asl1);
    GL16(bp0 + k0, bsl0);
    GL16(bp1 + k0, bsl1);
    __syncthreads();
    bf16x8 af[4], bfr[4];
#pragma unroll
    for (int m = 0; m < 4; ++m) af[m] = *(const bf16x8*)(As + (wm + m * 16 + lr) * 32 + lg * 8);
#pragma unroll
    for (int n = 0; n < 4; ++n) bfr[n] = *(const bf16x8*)(Bs + (wn + n * 16 + lr) * 32 + lg * 8);
#pragma unroll
    for (int m = 0; m < 4; ++m)
#pragma unroll
      for (int n = 0; n < 4; ++n)
        acc[m][n] = __builtin_amdgcn_mfma_f32_16x16x32_bf16(af[m], bfr[n], acc[m][n], 0, 0, 0);
    __syncthreads();
  }
#pragma unroll
  for (int m = 0; m < 4; ++m) {
    int row = m0 + wm + m * 16 + lg * 4;
#pragma unroll
    for (int n = 0; n < 4; ++n) {
      int col = n0 + wn + n * 16 + lr;
#pragma unroll
      for (int r = 0; r < 4; ++r) {
        if (OUT_BF16)
          ((unsigned short*)Cout)[(size_t)(row + r) * N + col] = f2bf(acc[m][n][r]);
        else
          ((float*)Cout)[(size_t)(row + r) * N + col] = acc[m][n][r];
      }
    }
  }
}

// ---------------- flash attention v6: 4 waves / 128-row q-tile, K+V LDS dbuf ----------------
// grid (16 qtiles big-first, 32 heads), block 256. Wave w owns q-rows qt*128+w*32..+31.
// Per kv-tile (64 keys): K[64][64] + VT[64 d][64 keys] staged via GL16, XOR-swizzled.
__global__ __launch_bounds__(256) void attn6_kernel(const unsigned short* __restrict__ Q,
                                                    const unsigned short* __restrict__ KV,
                                                    const unsigned short* __restrict__ VT,
                                                    const float* __restrict__ cost,
                                                    const float* __restrict__ sint,
                                                    const float* __restrict__ mask,
                                                    unsigned short* __restrict__ AO) {
  __shared__ __align__(16) unsigned short sm[2][8192];   // per buf: K 4096 | VT 4096 elems
  const int tid = threadIdx.x;
  const int w = tid >> 6, l = tid & 63;
  const int hi = l >> 5, l31 = l & 31;
  const int h = blockIdx.y, kvh = h >> 2;
  const int qt = 15 - blockIdx.x;        // big blocks first
  const int qrow = qt * 128 + w * 32 + l31;
  const int swz = (l & 7) << 4;
  const int hi16 = hi << 4;
  const float DEFER_T = 11.5415603f;     // 8 * log2(e)
  const int nt = 2 * qt + 2;             // kv tiles
  const int dt = 2 * qt + (w >> 1);      // this wave's diagonal tile

  const int strow = l >> 3;
  const int scol = ((l & 7) ^ (strow & 7)) * 8;    // pre-swizzled source column (elems)
  const unsigned short* kpA = KV + (size_t)(w * 8 + strow) * 1024 + kvh * 64 + scol;
  const unsigned short* kpB = kpA + (size_t)32 * 1024;
  const unsigned short* vpA = VT + (size_t)(kvh * 64 + w * 8 + strow) * QLEN + scol;
  const unsigned short* vpB = vpA + (size_t)32 * QLEN;

#define STAGE(kt_, b_) do { \
    unsigned short* smb_ = &sm[b_][0]; \
    GL16(kpA + (size_t)(kt_) * 65536, smb_ + w * 512); \
    GL16(kpB + (size_t)(kt_) * 65536, smb_ + 2048 + w * 512); \
    GL16(vpA + (size_t)(kt_) * 64,    smb_ + 4096 + w * 512); \
    GL16(vpB + (size_t)(kt_) * 64,    smb_ + 6144 + w * 512); \
  } while (0)

  // ---- load Q (B-frag layout) + fused RoPE; scale folds 1/8 and log2(e) ----
  const float QSC = 0.125f * 1.44269504088896340736f;
  const unsigned short* qp = Q + (size_t)qrow * HIDDEN + h * HD + hi * 8;
  bf16x8 qv0 = *(const bf16x8*)qp;
  bf16x8 qv1 = *(const bf16x8*)(qp + 16);
  bf16x8 qv2 = *(const bf16x8*)(qp + 32);
  bf16x8 qv3 = *(const bf16x8*)(qp + 48);
  const float* cbp = cost + qrow * 32 + hi * 8;
  const float* sbp = sint + qrow * 32 + hi * 8;
  f32x4 ca0 = *(const f32x4*)cbp,        ca1 = *(const f32x4*)(cbp + 4);
  f32x4 cB0 = *(const f32x4*)(cbp + 16), cB1 = *(const f32x4*)(cbp + 20);
  f32x4 sa0 = *(const f32x4*)sbp,        sa1 = *(const f32x4*)(sbp + 4);
  f32x4 sB0 = *(const f32x4*)(sbp + 16), sB1 = *(const f32x4*)(sbp + 20);
  bf16x8 qr0, qr1, qr2, qr3;
#pragma unroll
  for (int j = 0; j < 8; ++j) {
    float cosA = j < 4 ? ca0[j] : ca1[j - 4];
    float sinA = j < 4 ? sa0[j] : sa1[j - 4];
    float cosB = j < 4 ? cB0[j] : cB1[j - 4];
    float sinB = j < 4 ? sB0[j] : sB1[j - 4];
    float x0 = bf2f((unsigned short)qv0[j]);
    float x1 = bf2f((unsigned short)qv1[j]);
    float x2 = bf2f((unsigned short)qv2[j]);
    float x3 = bf2f((unsigned short)qv3[j]);
    qr0[j] = (short)f2bf((x0 * cosA - x2 * sinA) * QSC);
    qr1[j] = (short)f2bf((x1 * cosB - x3 * sinB) * QSC);
    qr2[j] = (short)f2bf((x2 * cosA + x0 * sinA) * QSC);
    qr3[j] = (short)f2bf((x3 * cosB + x1 * sinB) * QSC);
  }

  f32x16 O0 = {}, O1 = {};
  float mR = -1e30f, sR = 0.f;
  int cur = 0;
  STAGE(0, 0);
  __syncthreads();

  for (int kt = 0; kt < nt; ++kt) {
    if (kt + 1 < nt) STAGE(kt + 1, cur ^ 1);

    if (kt <= dt) {    // wave-uniform; skip fully-masked tile for lower-half waves
      const char* Kc = (const char*)&sm[cur][0];
      const char* Vc = Kc + 8192;

      // ---- S^T = K * Q^T : C[key][q], col = l31 = q ----
      f32x16 sA = {}, sB = {};
#define KF(half, dc) (*(const bf16x8*)(Kc + (((half) * 32 + l31) << 7) + ((((dc) * 32 + hi16)) ^ swz)))
      sA = MFMA32(KF(0, 0), qr0, sA);
      sA = MFMA32(KF(0, 1), qr1, sA);
      sA = MFMA32(KF(0, 2), qr2, sA);
      sA = MFMA32(KF(0, 3), qr3, sA);
      sB = MFMA32(KF(1, 0), qr0, sB);
      sB = MFMA32(KF(1, 1), qr1, sB);
      sB = MFMA32(KF(1, 2), qr2, sB);
      sB = MFMA32(KF(1, 3), qr3, sB);
#undef KF

      if (kt == dt) {   // causal mask on this wave's diagonal tile
#pragma unroll
        for (int r = 0; r < 16; ++r) {
          int key = kt * 64 + (r & 3) + 8 * (r >> 2) + 4 * hi;
          if (key > qrow) sA[r] = -1e30f;
          if (key + 32 > qrow) sB[r] = -1e30f;
        }
      }

      // ---- online softmax, tree reductions (scores in log2 units) ----
#define MAX8(v, o) fmaxf(fmaxf(fmaxf(v[o], v[o+1]), fmaxf(v[o+2], v[o+3])), \
                         fmaxf(fmaxf(v[o+4], v[o+5]), fmaxf(v[o+6], v[o+7])))
      float mx = fmaxf(fmaxf(MAX8(sA, 0), MAX8(sA, 8)), fmaxf(MAX8(sB, 0), MAX8(sB, 8)));
#undef MAX8
      mx = fmaxf(mx, __shfl_xor(mx, 32));
      bool renorm = __any(mx - mR > DEFER_T);
      if (renorm) {
        float mn = fmaxf(mR, mx);
        float sc = exp2f(mR - mn);
        mR = mn;
        sR *= sc;
#pragma unroll
        for (int r = 0; r < 16; ++r) { O0[r] *= sc; O1[r] *= sc; }
      }
#pragma unroll
      for (int r = 0; r < 16; ++r) sA[r] = exp2f(sA[r] - mR);
#pragma unroll
      for (int r = 0; r < 16; ++r) sB[r] = exp2f(sB[r] - mR);
#define SUM8(v, o) (((v[o] + v[o+1]) + (v[o+2] + v[o+3])) + ((v[o+4] + v[o+5]) + (v[o+6] + v[o+7])))
      float rs = (SUM8(sA, 0) + SUM8(sA, 8)) + (SUM8(sB, 0) + SUM8(sB, 8));
#undef SUM8
      rs += __shfl_xor(rs, 32);
      sR += rs;

      // ---- P -> bf16 B-frags in-register (pack + half-exchange) ----
      bf16x8 pf[4];
#pragma unroll
      for (int kc = 0; kc < 4; ++kc) {
        const int r0 = (kc & 1) * 8;
        float p0, p1, p2, p3, p4, p5, p6, p7;
        if (kc & 2) { p0 = sB[r0+0]; p1 = sB[r0+1]; p2 = sB[r0+2]; p3 = sB[r0+3];
                      p4 = sB[r0+4]; p5 = sB[r0+5]; p6 = sB[r0+6]; p7 = sB[r0+7]; }
        else        { p0 = sA[r0+0]; p1 = sA[r0+1]; p2 = sA[r0+2]; p3 = sA[r0+3];
                      p4 = sA[r0+4]; p5 = sA[r0+5]; p6 = sA[r0+6]; p7 = sA[r0+7]; }
        unsigned a_ = pack_bf2(p0, p1);
        unsigned c_ = pack_bf2(p2, p3);
        unsigned b_ = pack_bf2(p4, p5);
        unsigned d_ = pack_bf2(p6, p7);
        unsigned ax = __shfl_xor(a_, 32), bx2 = __shfl_xor(b_, 32);
        unsigned cx = __shfl_xor(c_, 32), dx = __shfl_xor(d_, 32);
        union { unsigned u[4]; bf16x8 v; } uu;
        uu.u[0] = hi ? bx2 : a_;
        uu.u[1] = hi ? dx : c_;
        uu.u[2] = hi ? b_ : ax;
        uu.u[3] = hi ? d_ : cx;
        pf[kc] = uu.v;
      }

      // ---- PV: O^T += V^T * P^T ----
#define VF(n, kc) (*(const bf16x8*)(Vc + (((n) * 32 + l31) << 7) + ((((kc) * 32 + hi16)) ^ swz)))
      O0 = MFMA32(VF(0, 0), pf[0], O0);
      O1 = MFMA32(VF(1, 0), pf[0], O1);
      O0 = MFMA32(VF(0, 1), pf[1], O0);
      O1 = MFMA32(VF(1, 1), pf[1], O1);
      O0 = MFMA32(VF(0, 2), pf[2], O0);
      O1 = MFMA32(VF(1, 2), pf[2], O1);
      O0 = MFMA32(VF(0, 3), pf[3], O0);
      O1 = MFMA32(VF(1, 3), pf[3], O1);
#undef VF
    }

    __syncthreads();
    cur ^= 1;
  }

  // ---- epilogue ----
  float msk = mask[(size_t)h * QLEN + qrow];
  float inv = msk / sR;
  unsigned short* aop = AO + (size_t)qrow * HIDDEN + h * HD;
#pragma unroll
  for (int rp = 0; rp < 8; ++rp) {
    int r = rp * 2;
    int d0 = (r & 3) + 8 * (r >> 2) + 4 * hi;
    *(unsigned*)(aop + d0)      = pack_bf2(O0[r] * inv, O0[r + 1] * inv);
    *(unsigned*)(aop + 32 + d0) = pack_bf2(O1[r] * inv, O1[r + 1] * inv);
  }
#undef STAGE
}

// ---------------- launcher ----------------
extern "C" void kernel_launch(void* const* d_in, const int* in_sizes, int n_in,
                              void* d_out, int out_size, void* d_ws, size_t ws_size,
                              hipStream_t stream) {
  const float* hs    = (const float*)d_in[0];
  const float* Wq    = (const float*)d_in[1];
  const float* Wk    = (const float*)d_in[2];
  const float* Wv    = (const float*)d_in[3];
  const float* Wo    = (const float*)d_in[4];
  const float* Wpred = (const float*)d_in[5];
  const int*   pid   = (const int*)d_in[6];
  float* out = (float*)d_out;

  unsigned short* hsb = (unsigned short*)d_ws;          // 4194304
  unsigned short* Wqb = hsb + 4194304;                  // 4194304 (contig with Wkb, Wvb)
  unsigned short* Wkb = Wqb + 4194304;                  // 1048576
  unsigned short* Wvb = Wkb + 1048576;                  // 1048576
  unsigned short* Wob = Wvb + 1048576;                  // 4194304
  unsigned short* Qb  = Wob + 4194304;                  // 4194304
  unsigned short* KVb = Qb  + 4194304;                  // 2097152 ([2048][1024]: K 0-511 | V 512-1023)
  unsigned short* AOb = KVb + 2097152;                  // 4194304
  float* maskb = (float*)(AOb + 4194304);               // 65536 f32
  float* cost  = maskb + 65536;                         // 65536 f32
  float* sint  = cost + 65536;                          // 65536 f32
  float* WpT   = sint + 65536;                          // 65536 f32
  double* hmp  = (double*)(WpT + 65536);                // 262144 f64
  unsigned short* VTb = hsb;   // hsb dead after projections; reuse for V^T [512][2048]

  cvt_all_kernel<<<2048, 256, 0, stream>>>(hs, Wq, Wk, Wv, Wo, hsb, Wqb, Wkb, Wvb, Wob);

  rope_table_kernel<<<256, 256, 0, stream>>>(pid, cost, sint);

  wpt_kernel<<<8, 256, 0, stream>>>(Wpred, WpT);
  headmask_part_kernel<<<dim3(256, 4), 256, 0, stream>>>(hs, WpT, hmp);
  headmask_comb_kernel<<<256, 256, 0, stream>>>(hmp, maskb);

  gemm_qkv_kernel<<<dim3(24, 16), 256, 0, stream>>>(hsb, Wqb, Qb, KVb);

  rope_apply_kernel<<<2048, 256, 0, stream>>>(KVb, cost, sint, NKV, 1024, QLEN * NKV * 32);

  transpose_kernel<<<dim3(8, 32), 256, 0, stream>>>(KVb + 512, VTb, QLEN, 512, 1024);

  attn6_kernel<<<dim3(16, 32), 256, 0, stream>>>(Qb, KVb, VTb, cost, sint, maskb, AOb);

  gemm2_kernel<false><<<dim3(16, 16), 256, 0, stream>>>(AOb, Wob, out, 2048, 2048);
}